// Round 1
// baseline (1071.637 us; speedup 1.0000x reference)
//
#include <hip/hip_runtime.h>
#include <stdint.h>

#define B_ 8
#define N_ 4000
#define C_ 80
#define NC_ (N_ * C_)          // 320000 candidates per image
#define KP_ 2048               // K_PRE
#define CAND_ 4096             // compaction capacity (>= KP_ + max bin count)
#define DET_ 100
#define HBINS_ 65536
#define NW_ 32                 // u64 words per NMS row (2048 bits)
#define CLIP_ 4.135166556742356f

__device__ __forceinline__ void decode_one(const float* __restrict__ pr,
                                           const float* __restrict__ d,
                                           float& x1, float& y1, float& x2, float& y2) {
  float p0 = pr[0], p1 = pr[1], p2 = pr[2], p3 = pr[3];
  float w = p2 - p0, h = p3 - p1;
  float cx = p0 + 0.5f * w, cy = p1 + 0.5f * h;
  float dx = d[0] / 10.0f, dy = d[1] / 10.0f;
  float dw = fminf(d[2] / 5.0f, CLIP_), dh = fminf(d[3] / 5.0f, CLIP_);
  float pcx = dx * w + cx, pcy = dy * h + cy;
  float pw = expf(dw) * w, ph = expf(dh) * h;
  x1 = pcx - 0.5f * pw; y1 = pcy - 0.5f * ph;
  x2 = pcx + 0.5f * pw; y2 = pcy + 0.5f * ph;
}

// K1: softmax + decode + validity -> score-bit keys + histogram of top 16 bits
__global__ void k_scores(const float* __restrict__ logits, const float* __restrict__ bbox,
                         const float* __restrict__ props, uint32_t* __restrict__ keys,
                         uint32_t* __restrict__ hist) {
  int id = blockIdx.x * blockDim.x + threadIdx.x;
  if (id >= B_ * N_) return;
  int b = id / N_, n = id % N_;
  const float* lp = logits + ((size_t)b * N_ + n) * (C_ + 1);
  float m = lp[0];
  for (int i = 1; i <= C_; ++i) m = fmaxf(m, lp[i]);
  float denom = 0.f;
  for (int i = 0; i <= C_; ++i) denom += expf(lp[i] - m);
  const float* pr = props + ((size_t)b * N_ + n) * 4;
  const float* dl = bbox + ((size_t)b * N_ + n) * ((C_ + 1) * 4);
  uint32_t* krow = keys + (size_t)b * NC_ + (size_t)n * C_;
  uint32_t* hb = hist + (size_t)b * HBINS_;
  for (int c = 0; c < C_; ++c) {
    float score = expf(lp[c + 1] - m) / denom;
    float x1, y1, x2, y2;
    decode_one(pr, dl + 4 * (c + 1), x1, y1, x2, y2);
    float area = (y2 - y1) * (x2 - x1);
    uint32_t key = 0;
    if (score > 0.01f && area > 0.1f) {
      key = __float_as_uint(score);
      atomicAdd(&hb[key >> 16], 1u);
    }
    krow[c] = key;
  }
}

// K2: per-image radix-select of threshold bin (>= KP_ survivors)
__global__ void k_select(const uint32_t* __restrict__ hist, uint32_t* __restrict__ thr) {
  int b = blockIdx.x;
  const uint32_t* hb = hist + (size_t)b * HBINS_;
  __shared__ uint32_t csum[256];
  int t = threadIdx.x;
  uint32_t s = 0;
  for (int i = 0; i < 256; ++i) s += hb[t * 256 + i];
  csum[t] = s;
  __syncthreads();
  if (t == 0) {
    uint32_t acc = 0;
    int T = 1;
    int chunk = -1;
    for (int c2 = 255; c2 >= 0; --c2) {
      if (acc + csum[c2] >= KP_) { chunk = c2; break; }
      acc += csum[c2];
    }
    if (chunk >= 0) {
      for (int bin = chunk * 256 + 255; bin >= chunk * 256; --bin) {
        acc += hb[bin];
        if (acc >= KP_) { T = bin; break; }
      }
    }
    thr[b] = ((uint32_t)T) << 16;
  }
}

// K3: compact surviving keys as 64-bit sortable (score_bits<<32)|~idx
__global__ void k_compact(const uint32_t* __restrict__ keys, const uint32_t* __restrict__ thr,
                          uint32_t* __restrict__ cnt, unsigned long long* __restrict__ cand) {
  int g = blockIdx.x * blockDim.x + threadIdx.x;
  if (g >= B_ * NC_) return;
  int b = g / NC_;
  uint32_t key = keys[g];
  if (key >= thr[b]) {
    uint32_t pos = atomicAdd(&cnt[b], 1u);
    if (pos < CAND_) {
      uint32_t idx = (uint32_t)(g - b * NC_);
      cand[(size_t)b * CAND_ + pos] =
          ((unsigned long long)key << 32) | (uint32_t)(~idx);
    }
  }
}

// K4: per-image bitonic sort (4096, LDS) -> top 2048, re-decode + NMS offset
__global__ __launch_bounds__(1024) void k_sort_topk(
    const unsigned long long* __restrict__ cand, const uint32_t* __restrict__ cnt,
    const float* __restrict__ bbox, const float* __restrict__ props,
    float* __restrict__ topScore, int* __restrict__ topLabel,
    float* __restrict__ topBox, float* __restrict__ nmsBox) {
  __shared__ unsigned long long sh[CAND_];
  int b = blockIdx.x, t = threadIdx.x;
  uint32_t m = cnt[b];
  if (m > CAND_) m = CAND_;
  for (int i = t; i < CAND_; i += 1024)
    sh[i] = (i < (int)m) ? cand[(size_t)b * CAND_ + i] : 0ull;
  __syncthreads();
  for (unsigned size = 2; size <= CAND_; size <<= 1) {
    for (unsigned stride = size >> 1; stride; stride >>= 1) {
      for (unsigned i = t; i < CAND_; i += 1024) {
        unsigned j = i ^ stride;
        if (j > i) {
          bool desc = ((i & size) == 0);
          unsigned long long a = sh[i], bb2 = sh[j];
          bool sw = desc ? (a < bb2) : (a > bb2);
          if (sw) { sh[i] = bb2; sh[j] = a; }
        }
      }
      __syncthreads();
    }
  }
  for (int k = t; k < KP_; k += 1024) {
    unsigned long long key = sh[k];
    size_t o = (size_t)b * KP_ + k;
    if (key == 0ull) {
      topScore[o] = -1.0f;
      topLabel[o] = 0;
      for (int j2 = 0; j2 < 4; ++j2) { topBox[o * 4 + j2] = 0.f; nmsBox[o * 4 + j2] = 0.f; }
      continue;
    }
    uint32_t sbits = (uint32_t)(key >> 32);
    uint32_t idx = ~((uint32_t)key);
    int n = idx / C_, c = idx % C_;
    const float* pr = props + ((size_t)b * N_ + n) * 4;
    const float* d = bbox + ((size_t)b * N_ + n) * ((C_ + 1) * 4) + 4 * (c + 1);
    float x1, y1, x2, y2;
    decode_one(pr, d, x1, y1, x2, y2);
    float off = (float)(c + 1) * 4096.0f;
    topScore[o] = __uint_as_float(sbits);
    topLabel[o] = c + 1;
    topBox[o * 4 + 0] = x1; topBox[o * 4 + 1] = y1;
    topBox[o * 4 + 2] = x2; topBox[o * 4 + 3] = y2;
    nmsBox[o * 4 + 0] = x1 + off; nmsBox[o * 4 + 1] = y1 + off;
    nmsBox[o * 4 + 2] = x2 + off; nmsBox[o * 4 + 3] = y2 + off;
  }
}

// K5: suppression bitmatrix: bit (i, j) set iff j>i and IoU(i,j) > 0.5
__global__ void k_supmat(const float* __restrict__ nmsBox, unsigned long long* __restrict__ sup) {
  int blk = blockIdx.x;
  int b = blk >> 8;                                  // 256 blocks per image
  int local = (blk & 255) * 256 + threadIdx.x;       // 0..65535 -> (i, w)
  int i = local >> 5, w2 = local & 31;
  const float4* boxes = (const float4*)(nmsBox + (size_t)b * KP_ * 4);
  float4 bi = boxes[i];
  float areai = fmaxf(bi.z - bi.x, 0.f) * fmaxf(bi.w - bi.y, 0.f);
  unsigned long long bits = 0;
  int lane = threadIdx.x & 63;
  for (int jj2 = 0; jj2 < 64; ++jj2) {
    int jj = (jj2 + lane) & 63;   // stagger to avoid same-bank bursts
    int j = w2 * 64 + jj;
    if (j > i) {
      float4 bj = boxes[j];
      float areaj = fmaxf(bj.z - bj.x, 0.f) * fmaxf(bj.w - bj.y, 0.f);
      float ltx = fmaxf(bi.x, bj.x), lty = fmaxf(bi.y, bj.y);
      float rbx = fminf(bi.z, bj.z), rby = fminf(bi.w, bj.w);
      float iw = fmaxf(rbx - ltx, 0.f), ih = fmaxf(rby - lty, 0.f);
      float inter = iw * ih;
      float uni = areai + areaj - inter;
      float iou = inter / fmaxf(uni, 1e-9f);
      if (iou > 0.5f) bits |= (1ull << jj);
    }
  }
  sup[((size_t)b * KP_ + i) * NW_ + w2] = bits;
}

// K6: serial greedy scan, one wave per image, lane w owns removed-word w
__global__ void k_nms_scan(const unsigned long long* __restrict__ sup,
                           const float* __restrict__ topScore,
                           float* __restrict__ finalScore) {
  int b = blockIdx.x, lane = threadIdx.x;  // 64 threads
  unsigned long long removed = 0;
  if (lane < NW_) {
    for (int j = 0; j < 64; ++j) {
      float s = topScore[(size_t)b * KP_ + lane * 64 + j];
      if (!(s > 0.0f)) removed |= (1ull << j);   // keep0 == false
    }
  }
  const unsigned long long* base = sup + (size_t)b * KP_ * NW_;
  unsigned long long nxt = (lane < NW_) ? base[lane] : 0ull;
  for (int i = 0; i < KP_; ++i) {
    unsigned long long row = nxt;
    if (lane < NW_ && i + 1 < KP_) nxt = base[(size_t)(i + 1) * NW_ + lane];
    int wi = i >> 6, bi2 = i & 63;
    unsigned long long rw =
        (unsigned long long)__shfl((long long)removed, wi, 64);
    if (!((rw >> bi2) & 1ull)) {
      if (lane < NW_) removed |= row;
    }
  }
  if (lane < NW_) {
    for (int j = 0; j < 64; ++j) {
      size_t o = (size_t)b * KP_ + lane * 64 + j;
      finalScore[o] = ((removed >> j) & 1ull) ? -1.0f : topScore[o];
    }
  }
}

// K7: final stable top-100 + output
__global__ __launch_bounds__(1024) void k_final(
    const float* __restrict__ finalScore, const float* __restrict__ topBox,
    const int* __restrict__ topLabel, float* __restrict__ out) {
  __shared__ unsigned long long sh[KP_];
  int b = blockIdx.x, t = threadIdx.x;
  for (int i = t; i < KP_; i += 1024) {
    float f = finalScore[(size_t)b * KP_ + i];
    uint32_t u = __float_as_uint(f);
    u = (u & 0x80000000u) ? ~u : (u | 0x80000000u);  // total-order transform
    sh[i] = ((unsigned long long)u << 32) | (uint32_t)(~(uint32_t)i);
  }
  __syncthreads();
  for (unsigned size = 2; size <= KP_; size <<= 1) {
    for (unsigned stride = size >> 1; stride; stride >>= 1) {
      for (unsigned i = t; i < KP_; i += 1024) {
        unsigned j = i ^ stride;
        if (j > i) {
          bool desc = ((i & size) == 0);
          unsigned long long a = sh[i], bb2 = sh[j];
          bool sw = desc ? (a < bb2) : (a > bb2);
          if (sw) { sh[i] = bb2; sh[j] = a; }
        }
      }
      __syncthreads();
    }
  }
  if (t < DET_) {
    unsigned long long key = sh[t];
    uint32_t k = ~((uint32_t)key);
    size_t src = (size_t)b * KP_ + k;
    float score = finalScore[src];
    out[((size_t)b * DET_ + t) * 4 + 0] = topBox[src * 4 + 0];
    out[((size_t)b * DET_ + t) * 4 + 1] = topBox[src * 4 + 1];
    out[((size_t)b * DET_ + t) * 4 + 2] = topBox[src * 4 + 2];
    out[((size_t)b * DET_ + t) * 4 + 3] = topBox[src * 4 + 3];
    out[B_ * DET_ * 4 + (size_t)b * DET_ + t] = score;
    out[B_ * DET_ * 4 + B_ * DET_ + (size_t)b * DET_ + t] = (float)topLabel[src];
  }
}

extern "C" void kernel_launch(void* const* d_in, const int* in_sizes, int n_in,
                              void* d_out, int out_size, void* d_ws, size_t ws_size,
                              hipStream_t stream) {
  const float* label_pre = (const float*)d_in[0];
  const float* bbox_pre = (const float*)d_in[1];
  const float* props = (const float*)d_in[2];
  float* out = (float*)d_out;

  char* ws = (char*)d_ws;
  size_t off = 0;
  auto alloc = [&](size_t bytes) -> void* {
    void* p = ws + off;
    off = (off + bytes + 255) & ~(size_t)255;
    return p;
  };

  uint32_t* keys = (uint32_t*)alloc((size_t)B_ * NC_ * 4);
  // ---- zero-init region (one memset): hist, cnt, cand ----
  size_t zero_begin = off;
  uint32_t* hist = (uint32_t*)alloc((size_t)B_ * HBINS_ * 4);
  uint32_t* cnt = (uint32_t*)alloc((size_t)B_ * 4);
  unsigned long long* cand = (unsigned long long*)alloc((size_t)B_ * CAND_ * 8);
  size_t zero_end = off;
  // ---------------------------------------------------------
  uint32_t* thr = (uint32_t*)alloc((size_t)B_ * 4);
  float* topScore = (float*)alloc((size_t)B_ * KP_ * 4);
  int* topLabel = (int*)alloc((size_t)B_ * KP_ * 4);
  float* topBox = (float*)alloc((size_t)B_ * KP_ * 16);
  float* nmsBox = (float*)alloc((size_t)B_ * KP_ * 16);
  unsigned long long* sup = (unsigned long long*)alloc((size_t)B_ * KP_ * NW_ * 8);
  float* finalScore = (float*)alloc((size_t)B_ * KP_ * 4);

  if (off > ws_size) return;  // workspace too small -> fail visibly

  hipMemsetAsync(ws + zero_begin, 0, zero_end - zero_begin, stream);

  k_scores<<<(B_ * N_ + 255) / 256, 256, 0, stream>>>(label_pre, bbox_pre, props, keys, hist);
  k_select<<<B_, 256, 0, stream>>>(hist, thr);
  k_compact<<<(B_ * NC_ + 255) / 256, 256, 0, stream>>>(keys, thr, cnt, cand);
  k_sort_topk<<<B_, 1024, 0, stream>>>(cand, cnt, bbox_pre, props,
                                       topScore, topLabel, topBox, nmsBox);
  k_supmat<<<B_ * 256, 256, 0, stream>>>(nmsBox, sup);
  k_nms_scan<<<B_, 64, 0, stream>>>(sup, topScore, finalScore);
  k_final<<<B_, 1024, 0, stream>>>(finalScore, topBox, topLabel, out);
}

// Round 2
// 638.264 us; speedup vs baseline: 1.6790x; 1.6790x over previous
//
#include <hip/hip_runtime.h>
#include <stdint.h>

#define B_ 8
#define N_ 4000
#define C_ 80
#define NC_ (N_ * C_)          // 320000 candidates per image
#define KP_ 2048               // K_PRE
#define CAND_ 4096             // compaction capacity (>= KP_ + max bin count)
#define DET_ 100
#define HBINS_ 65536
#define NW_ 32                 // u64 words per NMS row (2048 bits)
#define CLIP_ 4.135166556742356f

typedef unsigned long long u64;

__device__ __forceinline__ void decode_one(const float* __restrict__ pr,
                                           const float* __restrict__ d,
                                           float& x1, float& y1, float& x2, float& y2) {
  float p0 = pr[0], p1 = pr[1], p2 = pr[2], p3 = pr[3];
  float w = p2 - p0, h = p3 - p1;
  float cx = p0 + 0.5f * w, cy = p1 + 0.5f * h;
  float dx = d[0] / 10.0f, dy = d[1] / 10.0f;
  float dw = fminf(d[2] / 5.0f, CLIP_), dh = fminf(d[3] / 5.0f, CLIP_);
  float pcx = dx * w + cx, pcy = dy * h + cy;
  float pw = expf(dw) * w, ph = expf(dh) * h;
  x1 = pcx - 0.5f * pw; y1 = pcy - 0.5f * ph;
  x2 = pcx + 0.5f * pw; y2 = pcy + 0.5f * ph;
}

// K1: softmax + decode + validity -> score-bit keys + histogram of top 16 bits
__global__ void k_scores(const float* __restrict__ logits, const float* __restrict__ bbox,
                         const float* __restrict__ props, uint32_t* __restrict__ keys,
                         uint32_t* __restrict__ hist) {
  int id = blockIdx.x * blockDim.x + threadIdx.x;
  if (id >= B_ * N_) return;
  int b = id / N_, n = id % N_;
  const float* lp = logits + ((size_t)b * N_ + n) * (C_ + 1);
  float m = lp[0];
  for (int i = 1; i <= C_; ++i) m = fmaxf(m, lp[i]);
  float denom = 0.f;
  for (int i = 0; i <= C_; ++i) denom += expf(lp[i] - m);
  const float* pr = props + ((size_t)b * N_ + n) * 4;
  const float* dl = bbox + ((size_t)b * N_ + n) * ((C_ + 1) * 4);
  uint32_t* krow = keys + (size_t)b * NC_ + (size_t)n * C_;
  uint32_t* hb = hist + (size_t)b * HBINS_;
  for (int c = 0; c < C_; ++c) {
    float score = expf(lp[c + 1] - m) / denom;
    float x1, y1, x2, y2;
    decode_one(pr, dl + 4 * (c + 1), x1, y1, x2, y2);
    float area = (y2 - y1) * (x2 - x1);
    uint32_t key = 0;
    if (score > 0.01f && area > 0.1f) {
      key = __float_as_uint(score);
      atomicAdd(&hb[key >> 16], 1u);
    }
    krow[c] = key;
  }
}

// K2: per-image radix-select of threshold bin (>= KP_ survivors), fully parallel
__global__ void k_select(const uint32_t* __restrict__ hist, uint32_t* __restrict__ thr) {
  int b = blockIdx.x;
  const uint32_t* hb = hist + (size_t)b * HBINS_;
  __shared__ uint32_t suf[257];
  __shared__ uint32_t cval[256];
  __shared__ int chunkSel;
  __shared__ uint32_t tailCnt;
  int t = threadIdx.x;
  if (t == 0) { chunkSel = -1; tailCnt = 0; }
  uint32_t s = 0;
  for (int i = 0; i < 256; ++i) s += hb[t * 256 + i];
  cval[t] = s;
  suf[t] = s;
  if (t == 0) suf[256] = 0;
  __syncthreads();
  // inclusive suffix scan over chunk sums
  for (int d = 1; d < 256; d <<= 1) {
    uint32_t add = (t + d < 256) ? suf[t + d] : 0;
    __syncthreads();
    suf[t] += add;
    __syncthreads();
  }
  // chunk where crossing occurs: suf[t] >= KP && suf[t+1] < KP
  if (suf[t] >= KP_ && suf[t + 1] < KP_) {
    chunkSel = t;
    tailCnt = suf[t + 1];
  }
  __syncthreads();
  int C2 = chunkSel;
  if (C2 < 0) {                  // total survivors < KP_: pass everything nonzero
    if (t == 0) thr[b] = 1u << 16;
    return;
  }
  uint32_t tail = tailCnt;
  uint32_t c2v = hb[C2 * 256 + t];
  suf[t] = c2v;
  if (t == 0) suf[256] = 0;
  __syncthreads();
  for (int d = 1; d < 256; d <<= 1) {
    uint32_t add = (t + d < 256) ? suf[t + d] : 0;
    __syncthreads();
    suf[t] += add;
    __syncthreads();
  }
  uint32_t mySuf = suf[t] + tail;
  uint32_t nextSuf = suf[t + 1] + tail;
  if (mySuf >= KP_ && nextSuf < KP_) {
    uint32_t T = (uint32_t)(C2 * 256 + t);
    if (T == 0) T = 1;
    thr[b] = T << 16;
  }
}

// K3: compact surviving keys as 64-bit sortable (score_bits<<32)|~idx
__global__ void k_compact(const uint32_t* __restrict__ keys, const uint32_t* __restrict__ thr,
                          uint32_t* __restrict__ cnt, u64* __restrict__ cand) {
  int g = blockIdx.x * blockDim.x + threadIdx.x;
  if (g >= B_ * NC_) return;
  int b = g / NC_;
  uint32_t key = keys[g];
  if (key >= thr[b]) {
    uint32_t pos = atomicAdd(&cnt[b], 1u);
    if (pos < CAND_) {
      uint32_t idx = (uint32_t)(g - b * NC_);
      cand[(size_t)b * CAND_ + pos] = ((u64)key << 32) | (uint32_t)(~idx);
    }
  }
}

// K4: per-image bitonic sort (4096, LDS) -> top 2048, re-decode + NMS offset
__global__ __launch_bounds__(1024) void k_sort_topk(
    const u64* __restrict__ cand, const uint32_t* __restrict__ cnt,
    const float* __restrict__ bbox, const float* __restrict__ props,
    float* __restrict__ topScore, int* __restrict__ topLabel,
    float* __restrict__ topBox, float* __restrict__ nmsBox) {
  __shared__ u64 sh[CAND_];
  int b = blockIdx.x, t = threadIdx.x;
  uint32_t m = cnt[b];
  if (m > CAND_) m = CAND_;
  for (int i = t; i < CAND_; i += 1024)
    sh[i] = (i < (int)m) ? cand[(size_t)b * CAND_ + i] : 0ull;
  __syncthreads();
  for (unsigned size = 2; size <= CAND_; size <<= 1) {
    for (unsigned stride = size >> 1; stride; stride >>= 1) {
      for (unsigned i = t; i < CAND_; i += 1024) {
        unsigned j = i ^ stride;
        if (j > i) {
          bool desc = ((i & size) == 0);
          u64 a = sh[i], bb2 = sh[j];
          bool sw = desc ? (a < bb2) : (a > bb2);
          if (sw) { sh[i] = bb2; sh[j] = a; }
        }
      }
      __syncthreads();
    }
  }
  for (int k = t; k < KP_; k += 1024) {
    u64 key = sh[k];
    size_t o = (size_t)b * KP_ + k;
    if (key == 0ull) {
      topScore[o] = -1.0f;
      topLabel[o] = 0;
      for (int j2 = 0; j2 < 4; ++j2) { topBox[o * 4 + j2] = 0.f; nmsBox[o * 4 + j2] = 0.f; }
      continue;
    }
    uint32_t sbits = (uint32_t)(key >> 32);
    uint32_t idx = ~((uint32_t)key);
    int n = idx / C_, c = idx % C_;
    const float* pr = props + ((size_t)b * N_ + n) * 4;
    const float* d = bbox + ((size_t)b * N_ + n) * ((C_ + 1) * 4) + 4 * (c + 1);
    float x1, y1, x2, y2;
    decode_one(pr, d, x1, y1, x2, y2);
    float off = (float)(c + 1) * 4096.0f;
    topScore[o] = __uint_as_float(sbits);
    topLabel[o] = c + 1;
    topBox[o * 4 + 0] = x1; topBox[o * 4 + 1] = y1;
    topBox[o * 4 + 2] = x2; topBox[o * 4 + 3] = y2;
    nmsBox[o * 4 + 0] = x1 + off; nmsBox[o * 4 + 1] = y1 + off;
    nmsBox[o * 4 + 2] = x2 + off; nmsBox[o * 4 + 3] = y2 + off;
  }
}

// K5: suppression bitmatrix: bit (i, j) set iff j>i and IoU(i,j) > 0.5
__global__ void k_supmat(const float* __restrict__ nmsBox, u64* __restrict__ sup) {
  int blk = blockIdx.x;
  int b = blk >> 8;                                  // 256 blocks per image
  int local = (blk & 255) * 256 + threadIdx.x;       // 0..65535 -> (i, w)
  int i = local >> 5, w2 = local & 31;
  const float4* boxes = (const float4*)(nmsBox + (size_t)b * KP_ * 4);
  float4 bi = boxes[i];
  float areai = fmaxf(bi.z - bi.x, 0.f) * fmaxf(bi.w - bi.y, 0.f);
  u64 bits = 0;
  int lane = threadIdx.x & 63;
  for (int jj2 = 0; jj2 < 64; ++jj2) {
    int jj = (jj2 + lane) & 63;   // stagger to avoid same-bank bursts
    int j = w2 * 64 + jj;
    if (j > i) {
      float4 bj = boxes[j];
      float areaj = fmaxf(bj.z - bj.x, 0.f) * fmaxf(bj.w - bj.y, 0.f);
      float ltx = fmaxf(bi.x, bj.x), lty = fmaxf(bi.y, bj.y);
      float rbx = fminf(bi.z, bj.z), rby = fminf(bi.w, bj.w);
      float iw = fmaxf(rbx - ltx, 0.f), ih = fmaxf(rby - lty, 0.f);
      float inter = iw * ih;
      float uni = areai + areaj - inter;
      float iou = inter / fmaxf(uni, 1e-9f);
      if (iou > 0.5f) bits |= (1ull << jj);
    }
  }
  sup[((size_t)b * KP_ + i) * NW_ + w2] = bits;
}

// K6: chunked greedy NMS scan, one wave per image.
// Phase A: within-chunk 64-step greedy entirely in registers (readlane chain).
// Phase B: parallel OR of kept rows into future removed-words (pipelined loads).
__global__ __launch_bounds__(64) void k_nms_scan(const u64* __restrict__ sup,
                                                 const float* __restrict__ topScore,
                                                 float* __restrict__ finalScore) {
  int b = blockIdx.x, lane = threadIdx.x;  // 64 threads
  const u64* base = sup + (size_t)b * KP_ * NW_;
  // removed distributed: lane w (w < NW_) owns removed word w
  u64 removed = 0;
  if (lane < NW_) {
    for (int j = 0; j < 64; ++j) {
      float s = topScore[(size_t)b * KP_ + lane * 64 + j];
      if (!(s > 0.0f)) removed |= (1ull << j);   // keep0 == false
    }
  }
  // prefetch diag word of chunk 0 (lane i holds sup[c*64+i][c])
  u64 diag = base[(size_t)lane * NW_ + 0];
  for (int c = 0; c < NW_; ++c) {
    u64 diag_cur = diag;
    if (c + 1 < NW_)
      diag = base[(size_t)((c + 1) * 64 + lane) * NW_ + (c + 1)];
    // ---- phase A: serial greedy within chunk c (uniform across lanes) ----
    u64 rm = __shfl(removed, c);
    unsigned dlo = (unsigned)diag_cur, dhi = (unsigned)(diag_cur >> 32);
#pragma unroll
    for (int i = 0; i < 64; ++i) {
      u64 di = ((u64)__builtin_amdgcn_readlane(dhi, i) << 32) |
               (u64)__builtin_amdgcn_readlane(dlo, i);
      if (!((rm >> i) & 1ull)) rm |= di;
    }
    if (lane == c) removed = rm;
    u64 keep = ~rm;
    // ---- phase B: propagate kept rows of chunk c into words w > c ----
    int w2 = lane & 31, half = lane >> 5;
    u64 acc = 0;
    if (w2 > c) {
      const u64* rowbase = base + (size_t)c * 64 * NW_ + w2;
#pragma unroll
      for (int i2 = 0; i2 < 32; ++i2) {
        int i = half * 32 + i2;
        u64 row = rowbase[(size_t)i * NW_];
        acc |= ((keep >> i) & 1ull) ? row : 0ull;
      }
    }
    acc |= __shfl_xor(acc, 32);
    if (lane < NW_) removed |= acc;
  }
  if (lane < NW_) {
    for (int j = 0; j < 64; ++j) {
      size_t o = (size_t)b * KP_ + lane * 64 + j;
      finalScore[o] = ((removed >> j) & 1ull) ? -1.0f : topScore[o];
    }
  }
}

// K7: final stable top-100 + output
__global__ __launch_bounds__(1024) void k_final(
    const float* __restrict__ finalScore, const float* __restrict__ topBox,
    const int* __restrict__ topLabel, float* __restrict__ out) {
  __shared__ u64 sh[KP_];
  int b = blockIdx.x, t = threadIdx.x;
  for (int i = t; i < KP_; i += 1024) {
    float f = finalScore[(size_t)b * KP_ + i];
    uint32_t u = __float_as_uint(f);
    u = (u & 0x80000000u) ? ~u : (u | 0x80000000u);  // total-order transform
    sh[i] = ((u64)u << 32) | (uint32_t)(~(uint32_t)i);
  }
  __syncthreads();
  for (unsigned size = 2; size <= KP_; size <<= 1) {
    for (unsigned stride = size >> 1; stride; stride >>= 1) {
      for (unsigned i = t; i < KP_; i += 1024) {
        unsigned j = i ^ stride;
        if (j > i) {
          bool desc = ((i & size) == 0);
          u64 a = sh[i], bb2 = sh[j];
          bool sw = desc ? (a < bb2) : (a > bb2);
          if (sw) { sh[i] = bb2; sh[j] = a; }
        }
      }
      __syncthreads();
    }
  }
  if (t < DET_) {
    u64 key = sh[t];
    uint32_t k = ~((uint32_t)key);
    size_t src = (size_t)b * KP_ + k;
    float score = finalScore[src];
    out[((size_t)b * DET_ + t) * 4 + 0] = topBox[src * 4 + 0];
    out[((size_t)b * DET_ + t) * 4 + 1] = topBox[src * 4 + 1];
    out[((size_t)b * DET_ + t) * 4 + 2] = topBox[src * 4 + 2];
    out[((size_t)b * DET_ + t) * 4 + 3] = topBox[src * 4 + 3];
    out[B_ * DET_ * 4 + (size_t)b * DET_ + t] = score;
    out[B_ * DET_ * 4 + B_ * DET_ + (size_t)b * DET_ + t] = (float)topLabel[src];
  }
}

extern "C" void kernel_launch(void* const* d_in, const int* in_sizes, int n_in,
                              void* d_out, int out_size, void* d_ws, size_t ws_size,
                              hipStream_t stream) {
  const float* label_pre = (const float*)d_in[0];
  const float* bbox_pre = (const float*)d_in[1];
  const float* props = (const float*)d_in[2];
  float* out = (float*)d_out;

  char* ws = (char*)d_ws;
  size_t off = 0;
  auto alloc = [&](size_t bytes) -> void* {
    void* p = ws + off;
    off = (off + bytes + 255) & ~(size_t)255;
    return p;
  };

  uint32_t* keys = (uint32_t*)alloc((size_t)B_ * NC_ * 4);
  // ---- zero-init region (one memset): hist, cnt, cand ----
  size_t zero_begin = off;
  uint32_t* hist = (uint32_t*)alloc((size_t)B_ * HBINS_ * 4);
  uint32_t* cnt = (uint32_t*)alloc((size_t)B_ * 4);
  u64* cand = (u64*)alloc((size_t)B_ * CAND_ * 8);
  size_t zero_end = off;
  // ---------------------------------------------------------
  uint32_t* thr = (uint32_t*)alloc((size_t)B_ * 4);
  float* topScore = (float*)alloc((size_t)B_ * KP_ * 4);
  int* topLabel = (int*)alloc((size_t)B_ * KP_ * 4);
  float* topBox = (float*)alloc((size_t)B_ * KP_ * 16);
  float* nmsBox = (float*)alloc((size_t)B_ * KP_ * 16);
  u64* sup = (u64*)alloc((size_t)B_ * KP_ * NW_ * 8);
  float* finalScore = (float*)alloc((size_t)B_ * KP_ * 4);

  if (off > ws_size) return;  // workspace too small -> fail visibly

  hipMemsetAsync(ws + zero_begin, 0, zero_end - zero_begin, stream);

  k_scores<<<(B_ * N_ + 255) / 256, 256, 0, stream>>>(label_pre, bbox_pre, props, keys, hist);
  k_select<<<B_, 256, 0, stream>>>(hist, thr);
  k_compact<<<(B_ * NC_ + 255) / 256, 256, 0, stream>>>(keys, thr, cnt, cand);
  k_sort_topk<<<B_, 1024, 0, stream>>>(cand, cnt, bbox_pre, props,
                                       topScore, topLabel, topBox, nmsBox);
  k_supmat<<<B_ * 256, 256, 0, stream>>>(nmsBox, sup);
  k_nms_scan<<<B_, 64, 0, stream>>>(sup, topScore, finalScore);
  k_final<<<B_, 1024, 0, stream>>>(finalScore, topBox, topLabel, out);
}

// Round 4
// 577.642 us; speedup vs baseline: 1.8552x; 1.1049x over previous
//
#include <hip/hip_runtime.h>
#include <stdint.h>

#define B_ 8
#define N_ 4000
#define C_ 80
#define NC_ (N_ * C_)          // 320000 candidates per image
#define KP_ 2048               // K_PRE
#define CAND_ 4096             // compaction capacity = SLOTS_*SLOTCAP_
#define SLOTS_ 32
#define SLOTCAP_ 128
#define DET_ 100
#define HBINS_ 65536
#define NW_ 32                 // u64 words per NMS row (2048 bits)
#define CLIP_ 4.135166556742356f

typedef unsigned long long u64;

__device__ __forceinline__ void decode4(const float4 pr, const float4 d,
                                        float& x1, float& y1, float& x2, float& y2) {
  float w = pr.z - pr.x, h = pr.w - pr.y;
  float cx = pr.x + 0.5f * w, cy = pr.y + 0.5f * h;
  float dx = d.x / 10.0f, dy = d.y / 10.0f;
  float dw = fminf(d.z / 5.0f, CLIP_), dh = fminf(d.w / 5.0f, CLIP_);
  float pcx = dx * w + cx, pcy = dy * h + cy;
  float pw = expf(dw) * w, ph = expf(dh) * h;
  x1 = pcx - 0.5f * pw; y1 = pcy - 0.5f * ph;
  x2 = pcx + 0.5f * pw; y2 = pcy + 0.5f * ph;
}

// K0: per-proposal softmax max+denom (sequential sum order preserved bit-exactly).
__global__ __launch_bounds__(64) void k_softmax(const float* __restrict__ logits,
                                                float2* __restrict__ md) {
  __shared__ float lds[64 * 81];
  int blk = blockIdx.x, t = threadIdx.x;
  const float4* src = (const float4*)(logits + (size_t)blk * 64 * 81);
  for (int k = t; k < 64 * 81 / 4; k += 64) ((float4*)lds)[k] = src[k];
  __syncthreads();
  const float* lp = lds + t * 81;
  float m = lp[0];
  for (int i = 1; i <= C_; ++i) m = fmaxf(m, lp[i]);
  float denom = 0.f;
  for (int i = 0; i <= C_; ++i) denom += expf(lp[i] - m);
  md[blk * 64 + t] = make_float2(m, denom);
}

// K1: one wave per proposal, lane = class. Coalesced logits/deltas/keys.
__global__ __launch_bounds__(256) void k_scores2(const float* __restrict__ logits,
                                                 const float* __restrict__ bbox,
                                                 const float* __restrict__ props,
                                                 const float2* __restrict__ md,
                                                 uint32_t* __restrict__ keys,
                                                 uint32_t* __restrict__ hist) {
  int gid = blockIdx.x * 256 + threadIdx.x;
  int p = gid >> 6, lane = gid & 63;
  if (p >= B_ * N_) return;
  int b = p / N_;
  const float* lp = logits + (size_t)p * (C_ + 1);
  float2 md2 = md[p];
  float m = md2.x, denom = md2.y;
  float4 pr4 = ((const float4*)props)[p];
  const float4* dl4 = (const float4*)(bbox + (size_t)p * ((C_ + 1) * 4));
  uint32_t* krow = keys + (size_t)p * C_;
  uint32_t* hb = hist + (size_t)b * HBINS_;
#pragma unroll
  for (int pass = 0; pass < 2; ++pass) {
    int c = pass * 64 + lane;
    if (c < C_) {
      float score = expf(lp[c + 1] - m) / denom;
      float4 d = dl4[c + 1];
      float x1, y1, x2, y2;
      decode4(pr4, d, x1, y1, x2, y2);
      float area = (y2 - y1) * (x2 - x1);
      uint32_t key = 0;
      if (score > 0.01f && area > 0.1f) {
        key = __float_as_uint(score);
        atomicAdd(&hb[key >> 16], 1u);
      }
      krow[c] = key;
    }
  }
}

// K2: per-image radix-select of threshold bin (>= KP_ survivors), parallel scan
__global__ void k_select(const uint32_t* __restrict__ hist, uint32_t* __restrict__ thr) {
  int b = blockIdx.x;
  const uint32_t* hb = hist + (size_t)b * HBINS_;
  __shared__ uint32_t suf[257];
  __shared__ int chunkSel;
  __shared__ uint32_t tailCnt;
  int t = threadIdx.x;
  if (t == 0) { chunkSel = -1; tailCnt = 0; }
  uint32_t s = 0;
  const uint4* hb4 = (const uint4*)(hb + t * 256);
  for (int i = 0; i < 64; ++i) { uint4 v = hb4[i]; s += v.x + v.y + v.z + v.w; }
  suf[t] = s;
  if (t == 0) suf[256] = 0;
  __syncthreads();
  for (int d = 1; d < 256; d <<= 1) {
    uint32_t add = (t + d < 256) ? suf[t + d] : 0;
    __syncthreads();
    suf[t] += add;
    __syncthreads();
  }
  if (suf[t] >= KP_ && suf[t + 1] < KP_) { chunkSel = t; tailCnt = suf[t + 1]; }
  __syncthreads();
  int C2 = chunkSel;
  if (C2 < 0) { if (t == 0) thr[b] = 1u << 16; return; }
  uint32_t tail = tailCnt;
  uint32_t c2v = hb[C2 * 256 + t];
  suf[t] = c2v;
  if (t == 0) suf[256] = 0;
  __syncthreads();
  for (int d = 1; d < 256; d <<= 1) {
    uint32_t add = (t + d < 256) ? suf[t + d] : 0;
    __syncthreads();
    suf[t] += add;
    __syncthreads();
  }
  uint32_t mySuf = suf[t] + tail;
  uint32_t nextSuf = suf[t + 1] + tail;
  if (mySuf >= KP_ && nextSuf < KP_) {
    uint32_t T = (uint32_t)(C2 * 256 + t);
    if (T == 0) T = 1;
    thr[b] = T << 16;
  }
}

// K3: compact survivors into 32 slots/image; slot counters on distinct 64B lines.
__global__ void k_compact(const uint32_t* __restrict__ keys, const uint32_t* __restrict__ thr,
                          uint32_t* __restrict__ cnt, u64* __restrict__ cand) {
  int t = blockIdx.x * blockDim.x + threadIdx.x;   // B_*NC_/4 threads
  if (t >= B_ * NC_ / 4) return;
  uint4 k4 = ((const uint4*)keys)[t];
  int b = t / (NC_ / 4);
  int ti = t - b * (NC_ / 4);
  int slot = (ti >> 4) & (SLOTS_ - 1);
  uint32_t thrb = thr[b];
  uint32_t kv[4] = {k4.x, k4.y, k4.z, k4.w};
  int ns = 0;
#pragma unroll
  for (int q = 0; q < 4; ++q) ns += (kv[q] >= thrb) ? 1 : 0;
  if (ns == 0) return;
  uint32_t pos = atomicAdd(&cnt[(b * SLOTS_ + slot) * 16], (uint32_t)ns);
  u64* seg = cand + (size_t)b * CAND_ + slot * SLOTCAP_;
  uint32_t baseIdx = (uint32_t)(ti * 4);
#pragma unroll
  for (int q = 0; q < 4; ++q) {
    if (kv[q] >= thrb) {
      if (pos < SLOTCAP_)
        seg[pos] = ((u64)kv[q] << 32) | (uint32_t)(~(baseIdx + q));
      ++pos;
    }
  }
}

// K4: per-image bitonic sort (4096, LDS) -> top 2048, re-decode + NMS offset
__global__ __launch_bounds__(1024) void k_sort_topk(
    const u64* __restrict__ cand,
    const float* __restrict__ bbox, const float* __restrict__ props,
    float* __restrict__ topScore, int* __restrict__ topLabel,
    float* __restrict__ topBox, float* __restrict__ nmsBox) {
  __shared__ u64 sh[CAND_];
  int b = blockIdx.x, t = threadIdx.x;
  for (int i = t; i < CAND_; i += 1024)
    sh[i] = cand[(size_t)b * CAND_ + i];          // zeros where unfilled (memset)
  __syncthreads();
  for (unsigned size = 2; size <= CAND_; size <<= 1) {
    for (unsigned stride = size >> 1; stride; stride >>= 1) {
      for (unsigned i = t; i < CAND_; i += 1024) {
        unsigned j = i ^ stride;
        if (j > i) {
          bool desc = ((i & size) == 0);
          u64 a = sh[i], bb2 = sh[j];
          bool sw = desc ? (a < bb2) : (a > bb2);
          if (sw) { sh[i] = bb2; sh[j] = a; }
        }
      }
      __syncthreads();
    }
  }
  for (int k = t; k < KP_; k += 1024) {
    u64 key = sh[k];
    size_t o = (size_t)b * KP_ + k;
    if (key == 0ull) {
      topScore[o] = -1.0f;
      topLabel[o] = 0;
      for (int j2 = 0; j2 < 4; ++j2) { topBox[o * 4 + j2] = 0.f; nmsBox[o * 4 + j2] = 0.f; }
      continue;
    }
    uint32_t sbits = (uint32_t)(key >> 32);
    uint32_t idx = ~((uint32_t)key);
    int n = idx / C_, c = idx % C_;
    float4 pr4 = ((const float4*)props)[(size_t)b * N_ + n];
    float4 d = ((const float4*)(bbox + ((size_t)b * N_ + n) * ((C_ + 1) * 4)))[c + 1];
    float x1, y1, x2, y2;
    decode4(pr4, d, x1, y1, x2, y2);
    float off = (float)(c + 1) * 4096.0f;
    topScore[o] = __uint_as_float(sbits);
    topLabel[o] = c + 1;
    topBox[o * 4 + 0] = x1; topBox[o * 4 + 1] = y1;
    topBox[o * 4 + 2] = x2; topBox[o * 4 + 3] = y2;
    nmsBox[o * 4 + 0] = x1 + off; nmsBox[o * 4 + 1] = y1 + off;
    nmsBox[o * 4 + 2] = x2 + off; nmsBox[o * 4 + 3] = y2 + off;
  }
}

// K5: suppression bitmatrix, 64x64 tiles, j-boxes in LDS (broadcast reads).
// Only upper-triangle tiles (tj >= ti) are written; downstream never reads w < chunk.
__global__ __launch_bounds__(64) void k_supmat(const float* __restrict__ nmsBox,
                                               u64* __restrict__ sup) {
  int blk = blockIdx.x;
  int b = blk >> 10, rest = blk & 1023;
  int ti = rest >> 5, tj = rest & 31;
  if (tj < ti) return;                       // block-uniform early-out
  __shared__ float4 shj[64];
  int l = threadIdx.x;
  const float4* boxes = (const float4*)(nmsBox + (size_t)b * KP_ * 4);
  shj[l] = boxes[tj * 64 + l];
  int i = ti * 64 + l;
  float4 bi = boxes[i];
  float areai = fmaxf(bi.z - bi.x, 0.f) * fmaxf(bi.w - bi.y, 0.f);
  __syncthreads();
  u64 bits = 0;
  for (int jj = 0; jj < 64; ++jj) {
    int j = tj * 64 + jj;
    if (j > i) {
      float4 bj = shj[jj];
      float areaj = fmaxf(bj.z - bj.x, 0.f) * fmaxf(bj.w - bj.y, 0.f);
      float ltx = fmaxf(bi.x, bj.x), lty = fmaxf(bi.y, bj.y);
      float rbx = fminf(bi.z, bj.z), rby = fminf(bi.w, bj.w);
      float iw = fmaxf(rbx - ltx, 0.f), ih = fmaxf(rby - lty, 0.f);
      float inter = iw * ih;
      float uni = areai + areaj - inter;
      float iou = inter / fmaxf(uni, 1e-9f);
      if (iou > 0.5f) bits |= (1ull << jj);
    }
  }
  sup[((size_t)b * KP_ + i) * NW_ + tj] = bits;
}

// K6: chunked greedy NMS. Phase A: in-register readlane chain (serial 64).
// Phase B: coalesced loads of kept rows; OR only into words >= c (words < c are
// never-written lower-triangle — reading/ORing them was the round-3 bug).
__global__ __launch_bounds__(64) void k_nms_scan(const u64* __restrict__ sup,
                                                 const float* __restrict__ topScore,
                                                 float* __restrict__ finalScore) {
  int b = blockIdx.x, lane = threadIdx.x;
  const u64* base = sup + (size_t)b * KP_ * NW_;
  u64 removed = 0;
  if (lane < NW_) {
    for (int j = 0; j < 64; ++j) {
      float s = topScore[(size_t)b * KP_ + lane * 64 + j];
      if (!(s > 0.0f)) removed |= (1ull << j);   // keep0 == false
    }
  }
  u64 diag = base[(size_t)lane * NW_ + 0];
  for (int c = 0; c < NW_; ++c) {
    u64 diag_cur = diag;
    if (c + 1 < NW_)
      diag = base[(size_t)((c + 1) * 64 + lane) * NW_ + (c + 1)];
    u64 rm = __shfl(removed, c);
    unsigned dlo = (unsigned)diag_cur, dhi = (unsigned)(diag_cur >> 32);
#pragma unroll
    for (int i = 0; i < 64; ++i) {
      u64 di = ((u64)__builtin_amdgcn_readlane(dhi, i) << 32) |
               (u64)__builtin_amdgcn_readlane(dlo, i);
      if (!((rm >> i) & 1ull)) rm |= di;
    }
    if (lane == c) removed = rm;
    u64 keep = ~rm;                       // wave-uniform
    const u64* rowbase = base + (size_t)c * 64 * NW_;
    u64 acc = 0;
    if (lane < NW_ && lane >= c) {        // only valid (written) words
      for (int i2 = 0; i2 < 64; ++i2) {
        u64 row = rowbase[(size_t)i2 * NW_ + lane];
        acc |= ((keep >> i2) & 1ull) ? row : 0ull;
      }
      removed |= acc;
    }
  }
  if (lane < NW_) {
    for (int j = 0; j < 64; ++j) {
      size_t o = (size_t)b * KP_ + lane * 64 + j;
      finalScore[o] = ((removed >> j) & 1ull) ? -1.0f : topScore[o];
    }
  }
}

// K7: final stable top-100 + output
__global__ __launch_bounds__(1024) void k_final(
    const float* __restrict__ finalScore, const float* __restrict__ topBox,
    const int* __restrict__ topLabel, float* __restrict__ out) {
  __shared__ u64 sh[KP_];
  int b = blockIdx.x, t = threadIdx.x;
  for (int i = t; i < KP_; i += 1024) {
    float f = finalScore[(size_t)b * KP_ + i];
    uint32_t u = __float_as_uint(f);
    u = (u & 0x80000000u) ? ~u : (u | 0x80000000u);  // total-order transform
    sh[i] = ((u64)u << 32) | (uint32_t)(~(uint32_t)i);
  }
  __syncthreads();
  for (unsigned size = 2; size <= KP_; size <<= 1) {
    for (unsigned stride = size >> 1; stride; stride >>= 1) {
      for (unsigned i = t; i < KP_; i += 1024) {
        unsigned j = i ^ stride;
        if (j > i) {
          bool desc = ((i & size) == 0);
          u64 a = sh[i], bb2 = sh[j];
          bool sw = desc ? (a < bb2) : (a > bb2);
          if (sw) { sh[i] = bb2; sh[j] = a; }
        }
      }
      __syncthreads();
    }
  }
  if (t < DET_) {
    u64 key = sh[t];
    uint32_t k = ~((uint32_t)key);
    size_t src = (size_t)b * KP_ + k;
    float score = finalScore[src];
    out[((size_t)b * DET_ + t) * 4 + 0] = topBox[src * 4 + 0];
    out[((size_t)b * DET_ + t) * 4 + 1] = topBox[src * 4 + 1];
    out[((size_t)b * DET_ + t) * 4 + 2] = topBox[src * 4 + 2];
    out[((size_t)b * DET_ + t) * 4 + 3] = topBox[src * 4 + 3];
    out[B_ * DET_ * 4 + (size_t)b * DET_ + t] = score;
    out[B_ * DET_ * 4 + B_ * DET_ + (size_t)b * DET_ + t] = (float)topLabel[src];
  }
}

extern "C" void kernel_launch(void* const* d_in, const int* in_sizes, int n_in,
                              void* d_out, int out_size, void* d_ws, size_t ws_size,
                              hipStream_t stream) {
  const float* label_pre = (const float*)d_in[0];
  const float* bbox_pre = (const float*)d_in[1];
  const float* props = (const float*)d_in[2];
  float* out = (float*)d_out;

  char* ws = (char*)d_ws;
  size_t off = 0;
  auto alloc = [&](size_t bytes) -> void* {
    void* p = ws + off;
    off = (off + bytes + 255) & ~(size_t)255;
    return p;
  };

  uint32_t* keys = (uint32_t*)alloc((size_t)B_ * NC_ * 4);
  float2* md = (float2*)alloc((size_t)B_ * N_ * 8);
  // ---- zero-init region (one memset): hist, cnt, cand ----
  size_t zero_begin = off;
  uint32_t* hist = (uint32_t*)alloc((size_t)B_ * HBINS_ * 4);
  uint32_t* cnt = (uint32_t*)alloc((size_t)B_ * SLOTS_ * 16 * 4);
  u64* cand = (u64*)alloc((size_t)B_ * CAND_ * 8);
  size_t zero_end = off;
  // ---------------------------------------------------------
  uint32_t* thr = (uint32_t*)alloc((size_t)B_ * 4);
  float* topScore = (float*)alloc((size_t)B_ * KP_ * 4);
  int* topLabel = (int*)alloc((size_t)B_ * KP_ * 4);
  float* topBox = (float*)alloc((size_t)B_ * KP_ * 16);
  float* nmsBox = (float*)alloc((size_t)B_ * KP_ * 16);
  u64* sup = (u64*)alloc((size_t)B_ * KP_ * NW_ * 8);
  float* finalScore = (float*)alloc((size_t)B_ * KP_ * 4);

  if (off > ws_size) return;  // workspace too small -> fail visibly

  hipMemsetAsync(ws + zero_begin, 0, zero_end - zero_begin, stream);

  k_softmax<<<B_ * N_ / 64, 64, 0, stream>>>(label_pre, md);
  k_scores2<<<B_ * N_ / 4, 256, 0, stream>>>(label_pre, bbox_pre, props, md, keys, hist);
  k_select<<<B_, 256, 0, stream>>>(hist, thr);
  k_compact<<<(B_ * NC_ / 4 + 255) / 256, 256, 0, stream>>>(keys, thr, cnt, cand);
  k_sort_topk<<<B_, 1024, 0, stream>>>(cand, bbox_pre, props,
                                       topScore, topLabel, topBox, nmsBox);
  k_supmat<<<B_ * 1024, 64, 0, stream>>>(nmsBox, sup);
  k_nms_scan<<<B_, 64, 0, stream>>>(sup, topScore, finalScore);
  k_final<<<B_, 1024, 0, stream>>>(finalScore, topBox, topLabel, out);
}

// Round 5
// 390.946 us; speedup vs baseline: 2.7411x; 1.4775x over previous
//
#include <hip/hip_runtime.h>
#include <stdint.h>

#define B_ 8
#define N_ 4000
#define C_ 80
#define NC_ (N_ * C_)          // 320000 candidates per image
#define KP_ 2048               // K_PRE
#define CAND_ 4096             // compaction capacity = SLOTS_*SLOTCAP_
#define SLOTS_ 32
#define SLOTCAP_ 128
#define DET_ 100
#define NW_ 32                 // u64 words per NMS row (2048 bits)
#define CLIP_ 4.135166556742356f

#define PB_ 16                 // proposals per k_scores2 block
#define IB_ (N_ / PB_)         // 250 blocks per image
#define CB_ 64                 // coarse bins ((key>>20)-960 in [2,55] for score in (0.01,1))
#define FB_ 128                // fine bins (key>>13 & 127)

typedef unsigned long long u64;

__device__ __forceinline__ void decode4(const float4 pr, const float4 d,
                                        float& x1, float& y1, float& x2, float& y2) {
  float w = pr.z - pr.x, h = pr.w - pr.y;
  float cx = pr.x + 0.5f * w, cy = pr.y + 0.5f * h;
  float dx = d.x / 10.0f, dy = d.y / 10.0f;
  float dw = fminf(d.z / 5.0f, CLIP_), dh = fminf(d.w / 5.0f, CLIP_);
  float pcx = dx * w + cx, pcy = dy * h + cy;
  float pw = expf(dw) * w, ph = expf(dh) * h;
  x1 = pcx - 0.5f * pw; y1 = pcy - 0.5f * ph;
  x2 = pcx + 0.5f * pw; y2 = pcy + 0.5f * ph;
}

// K0: per-proposal softmax max+denom (sequential sum order preserved bit-exactly).
__global__ __launch_bounds__(64) void k_softmax(const float* __restrict__ logits,
                                                float2* __restrict__ md) {
  __shared__ float lds[64 * 81];
  int blk = blockIdx.x, t = threadIdx.x;
  const float4* src = (const float4*)(logits + (size_t)blk * 64 * 81);
  for (int k = t; k < 64 * 81 / 4; k += 64) ((float4*)lds)[k] = src[k];
  __syncthreads();
  const float* lp = lds + t * 81;
  float m = lp[0];
  for (int i = 1; i <= C_; ++i) m = fmaxf(m, lp[i]);
  float denom = 0.f;
  for (int i = 0; i <= C_; ++i) denom += expf(lp[i] - m);
  md[blk * 64 + t] = make_float2(m, denom);
}

// K1: scores + validity keys + per-block coarse histogram (no global atomics).
__global__ __launch_bounds__(256) void k_scores2(const float* __restrict__ logits,
                                                 const float* __restrict__ bbox,
                                                 const float* __restrict__ props,
                                                 const float2* __restrict__ md,
                                                 uint32_t* __restrict__ keys,
                                                 uint32_t* __restrict__ blockHist) {
  __shared__ uint32_t hcnt[CB_];
  int blk = blockIdx.x;                 // 0 .. B_*IB_-1
  int b = blk / IB_, lb = blk - b * IB_;
  int p0 = lb * PB_;
  int t = threadIdx.x;
  if (t < CB_) hcnt[t] = 0;
  __syncthreads();
  const float4* props4 = (const float4*)props;
  const float4* bbox4 = (const float4*)bbox;
#pragma unroll
  for (int iter = 0; iter < PB_ * C_ / 256; ++iter) {   // 5 iters
    int e = iter * 256 + t;             // 0..1279
    int pp = e / C_, c = e - pp * C_;
    int p = b * N_ + p0 + pp;
    float lv = logits[(size_t)p * (C_ + 1) + c + 1];
    float2 md2 = md[p];
    float score = expf(lv - md2.x) / md2.y;
    uint32_t key = 0;
    if (score > 0.01f) {
      float4 pr4 = props4[p];
      float4 d = bbox4[(size_t)p * (C_ + 1) + c + 1];
      float x1, y1, x2, y2;
      decode4(pr4, d, x1, y1, x2, y2);
      float area = (y2 - y1) * (x2 - x1);
      if (area > 0.1f) {
        key = __float_as_uint(score);
        atomicAdd(&hcnt[(key >> 20) - 960], 1u);   // LDS atomic
      } else key = 0;
    }
    keys[(size_t)p * C_ + c] = key;
  }
  __syncthreads();
  if (t < CB_) blockHist[(size_t)blk * CB_ + t] = hcnt[t];
}

// K2: coarse select — one wave per image: reduce block hists + shfl suffix scan.
__global__ __launch_bounds__(64) void k_select(const uint32_t* __restrict__ blockHist,
                                               int* __restrict__ coarse,
                                               uint32_t* __restrict__ tailA,
                                               uint32_t* __restrict__ thr) {
  int b = blockIdx.x, lane = threadIdx.x;
  const uint32_t* hb = blockHist + (size_t)b * IB_ * CB_;
  uint32_t s = 0;
  for (int k = 0; k < IB_; ++k) s += hb[(size_t)k * CB_ + lane];
  // inclusive suffix scan across 64 lanes
  uint32_t v = s;
#pragma unroll
  for (int d = 1; d < 64; d <<= 1) {
    uint32_t o = __shfl_down(v, d);
    v += (lane + d < 64) ? o : 0;
  }
  uint32_t nxt = __shfl_down(v, 1);
  if (lane == 63) nxt = 0;
  uint32_t total = __shfl(v, 0);
  if (total < KP_) {
    if (lane == 0) { coarse[b] = -1; thr[b] = 1u; }
    return;
  }
  if (v >= KP_ && nxt < KP_) { coarse[b] = lane; tailA[b] = nxt; }
}

// K2b: fine histogram of keys inside the coarse bin (few thousand atomics total)
__global__ void k_refine(const uint32_t* __restrict__ keys, const int* __restrict__ coarse,
                         uint32_t* __restrict__ fineHist) {
  int t = blockIdx.x * blockDim.x + threadIdx.x;   // B_*NC_/4 threads
  if (t >= B_ * NC_ / 4) return;
  uint4 k4 = ((const uint4*)keys)[t];
  int b = t / (NC_ / 4);
  int cb = coarse[b];
  if (cb < 0) return;
  uint32_t want = (uint32_t)(cb + 960);
  uint32_t kv[4] = {k4.x, k4.y, k4.z, k4.w};
#pragma unroll
  for (int q = 0; q < 4; ++q)
    if ((kv[q] >> 20) == want)
      atomicAdd(&fineHist[b * FB_ + ((kv[q] >> 13) & (FB_ - 1))], 1u);
}

// K2c: fine select — one wave per image over 128 fine bins (2 per lane)
__global__ __launch_bounds__(64) void k_select2(const uint32_t* __restrict__ fineHist,
                                                const int* __restrict__ coarse,
                                                const uint32_t* __restrict__ tailA,
                                                uint32_t* __restrict__ thr) {
  int b = blockIdx.x, lane = threadIdx.x;
  int cb = coarse[b];
  if (cb < 0) return;                    // thr already set by k_select
  uint32_t f0 = fineHist[b * FB_ + 2 * lane];
  uint32_t f1 = fineHist[b * FB_ + 2 * lane + 1];
  uint32_t ps = f0 + f1;
  uint32_t v = ps;
#pragma unroll
  for (int d = 1; d < 64; d <<= 1) {
    uint32_t o = __shfl_down(v, d);
    v += (lane + d < 64) ? o : 0;
  }
  uint32_t nxt = __shfl_down(v, 1);
  if (lane == 63) nxt = 0;
  uint32_t tail = tailA[b];
  uint32_t S0 = v;              // S_fine(2*lane)
  uint32_t S1 = nxt + f1;       // S_fine(2*lane+1)
  bool c0 = (tail + S0 >= KP_);
  bool c1 = (tail + S1 >= KP_);
  bool cNext = (tail + nxt >= KP_);   // cond(2*lane+2)
  int ans = -1;
  if (c0 && !c1) ans = 2 * lane;
  if (c1 && !cNext) ans = 2 * lane + 1;
  if (ans >= 0)
    thr[b] = ((uint32_t)(cb + 960) << 20) | ((uint32_t)ans << 13);
}

// K3: compact survivors into 32 slots/image; slot counters on distinct 64B lines.
__global__ void k_compact(const uint32_t* __restrict__ keys, const uint32_t* __restrict__ thr,
                          uint32_t* __restrict__ cnt, u64* __restrict__ cand) {
  int t = blockIdx.x * blockDim.x + threadIdx.x;   // B_*NC_/4 threads
  if (t >= B_ * NC_ / 4) return;
  uint4 k4 = ((const uint4*)keys)[t];
  int b = t / (NC_ / 4);
  int ti = t - b * (NC_ / 4);
  int slot = (ti >> 4) & (SLOTS_ - 1);
  uint32_t thrb = thr[b];
  uint32_t kv[4] = {k4.x, k4.y, k4.z, k4.w};
  int ns = 0;
#pragma unroll
  for (int q = 0; q < 4; ++q) ns += (kv[q] >= thrb) ? 1 : 0;
  if (ns == 0) return;
  uint32_t pos = atomicAdd(&cnt[(b * SLOTS_ + slot) * 16], (uint32_t)ns);
  u64* seg = cand + (size_t)b * CAND_ + slot * SLOTCAP_;
  uint32_t baseIdx = (uint32_t)(ti * 4);
#pragma unroll
  for (int q = 0; q < 4; ++q) {
    if (kv[q] >= thrb) {
      if (pos < SLOTCAP_)
        seg[pos] = ((u64)kv[q] << 32) | (uint32_t)(~(baseIdx + q));
      ++pos;
    }
  }
}

// K4: per-image bitonic sort (4096, LDS) -> top 2048, re-decode + NMS offset
__global__ __launch_bounds__(1024) void k_sort_topk(
    const u64* __restrict__ cand,
    const float* __restrict__ bbox, const float* __restrict__ props,
    float* __restrict__ topScore, int* __restrict__ topLabel,
    float* __restrict__ topBox, float* __restrict__ nmsBox) {
  __shared__ u64 sh[CAND_];
  int b = blockIdx.x, t = threadIdx.x;
  for (int i = t; i < CAND_; i += 1024)
    sh[i] = cand[(size_t)b * CAND_ + i];          // zeros where unfilled (memset)
  __syncthreads();
  for (unsigned size = 2; size <= CAND_; size <<= 1) {
    for (unsigned stride = size >> 1; stride; stride >>= 1) {
      for (unsigned i = t; i < CAND_; i += 1024) {
        unsigned j = i ^ stride;
        if (j > i) {
          bool desc = ((i & size) == 0);
          u64 a = sh[i], bb2 = sh[j];
          bool sw = desc ? (a < bb2) : (a > bb2);
          if (sw) { sh[i] = bb2; sh[j] = a; }
        }
      }
      __syncthreads();
    }
  }
  for (int k = t; k < KP_; k += 1024) {
    u64 key = sh[k];
    size_t o = (size_t)b * KP_ + k;
    if (key == 0ull) {
      topScore[o] = -1.0f;
      topLabel[o] = 0;
      for (int j2 = 0; j2 < 4; ++j2) { topBox[o * 4 + j2] = 0.f; nmsBox[o * 4 + j2] = 0.f; }
      continue;
    }
    uint32_t sbits = (uint32_t)(key >> 32);
    uint32_t idx = ~((uint32_t)key);
    int n = idx / C_, c = idx % C_;
    float4 pr4 = ((const float4*)props)[(size_t)b * N_ + n];
    float4 d = ((const float4*)(bbox + ((size_t)b * N_ + n) * ((C_ + 1) * 4)))[c + 1];
    float x1, y1, x2, y2;
    decode4(pr4, d, x1, y1, x2, y2);
    float off = (float)(c + 1) * 4096.0f;
    topScore[o] = __uint_as_float(sbits);
    topLabel[o] = c + 1;
    topBox[o * 4 + 0] = x1; topBox[o * 4 + 1] = y1;
    topBox[o * 4 + 2] = x2; topBox[o * 4 + 3] = y2;
    nmsBox[o * 4 + 0] = x1 + off; nmsBox[o * 4 + 1] = y1 + off;
    nmsBox[o * 4 + 2] = x2 + off; nmsBox[o * 4 + 3] = y2 + off;
  }
}

// K5: suppression bitmatrix, 64x64 tiles, j-boxes in LDS (broadcast reads).
// Only upper-triangle tiles (tj >= ti) are written; downstream never reads w < chunk.
__global__ __launch_bounds__(64) void k_supmat(const float* __restrict__ nmsBox,
                                               u64* __restrict__ sup) {
  int blk = blockIdx.x;
  int b = blk >> 10, rest = blk & 1023;
  int ti = rest >> 5, tj = rest & 31;
  if (tj < ti) return;                       // block-uniform early-out
  __shared__ float4 shj[64];
  int l = threadIdx.x;
  const float4* boxes = (const float4*)(nmsBox + (size_t)b * KP_ * 4);
  shj[l] = boxes[tj * 64 + l];
  int i = ti * 64 + l;
  float4 bi = boxes[i];
  float areai = fmaxf(bi.z - bi.x, 0.f) * fmaxf(bi.w - bi.y, 0.f);
  __syncthreads();
  u64 bits = 0;
  for (int jj = 0; jj < 64; ++jj) {
    int j = tj * 64 + jj;
    if (j > i) {
      float4 bj = shj[jj];
      float areaj = fmaxf(bj.z - bj.x, 0.f) * fmaxf(bj.w - bj.y, 0.f);
      float ltx = fmaxf(bi.x, bj.x), lty = fmaxf(bi.y, bj.y);
      float rbx = fminf(bi.z, bj.z), rby = fminf(bi.w, bj.w);
      float iw = fmaxf(rbx - ltx, 0.f), ih = fmaxf(rby - lty, 0.f);
      float inter = iw * ih;
      float uni = areai + areaj - inter;
      float iou = inter / fmaxf(uni, 1e-9f);
      if (iou > 0.5f) bits |= (1ull << jj);
    }
  }
  sup[((size_t)b * KP_ + i) * NW_ + tj] = bits;
}

// K6: chunked greedy NMS. Phase A: in-register readlane chain (serial 64).
// Phase B: coalesced loads of kept rows; OR only into words >= c.
__global__ __launch_bounds__(64) void k_nms_scan(const u64* __restrict__ sup,
                                                 const float* __restrict__ topScore,
                                                 float* __restrict__ finalScore) {
  int b = blockIdx.x, lane = threadIdx.x;
  const u64* base = sup + (size_t)b * KP_ * NW_;
  u64 removed = 0;
  if (lane < NW_) {
    for (int j = 0; j < 64; ++j) {
      float s = topScore[(size_t)b * KP_ + lane * 64 + j];
      if (!(s > 0.0f)) removed |= (1ull << j);   // keep0 == false
    }
  }
  u64 diag = base[(size_t)lane * NW_ + 0];
  for (int c = 0; c < NW_; ++c) {
    u64 diag_cur = diag;
    if (c + 1 < NW_)
      diag = base[(size_t)((c + 1) * 64 + lane) * NW_ + (c + 1)];
    u64 rm = __shfl(removed, c);
    unsigned dlo = (unsigned)diag_cur, dhi = (unsigned)(diag_cur >> 32);
#pragma unroll
    for (int i = 0; i < 64; ++i) {
      u64 di = ((u64)__builtin_amdgcn_readlane(dhi, i) << 32) |
               (u64)__builtin_amdgcn_readlane(dlo, i);
      if (!((rm >> i) & 1ull)) rm |= di;
    }
    if (lane == c) removed = rm;
    u64 keep = ~rm;                       // wave-uniform
    const u64* rowbase = base + (size_t)c * 64 * NW_;
    u64 acc = 0;
    if (lane < NW_ && lane >= c) {        // only valid (written) words
      for (int i2 = 0; i2 < 64; ++i2) {
        u64 row = rowbase[(size_t)i2 * NW_ + lane];
        acc |= ((keep >> i2) & 1ull) ? row : 0ull;
      }
      removed |= acc;
    }
  }
  if (lane < NW_) {
    for (int j = 0; j < 64; ++j) {
      size_t o = (size_t)b * KP_ + lane * 64 + j;
      finalScore[o] = ((removed >> j) & 1ull) ? -1.0f : topScore[o];
    }
  }
}

// K7: final stable top-100 + output
__global__ __launch_bounds__(1024) void k_final(
    const float* __restrict__ finalScore, const float* __restrict__ topBox,
    const int* __restrict__ topLabel, float* __restrict__ out) {
  __shared__ u64 sh[KP_];
  int b = blockIdx.x, t = threadIdx.x;
  for (int i = t; i < KP_; i += 1024) {
    float f = finalScore[(size_t)b * KP_ + i];
    uint32_t u = __float_as_uint(f);
    u = (u & 0x80000000u) ? ~u : (u | 0x80000000u);  // total-order transform
    sh[i] = ((u64)u << 32) | (uint32_t)(~(uint32_t)i);
  }
  __syncthreads();
  for (unsigned size = 2; size <= KP_; size <<= 1) {
    for (unsigned stride = size >> 1; stride; stride >>= 1) {
      for (unsigned i = t; i < KP_; i += 1024) {
        unsigned j = i ^ stride;
        if (j > i) {
          bool desc = ((i & size) == 0);
          u64 a = sh[i], bb2 = sh[j];
          bool sw = desc ? (a < bb2) : (a > bb2);
          if (sw) { sh[i] = bb2; sh[j] = a; }
        }
      }
      __syncthreads();
    }
  }
  if (t < DET_) {
    u64 key = sh[t];
    uint32_t k = ~((uint32_t)key);
    size_t src = (size_t)b * KP_ + k;
    float score = finalScore[src];
    out[((size_t)b * DET_ + t) * 4 + 0] = topBox[src * 4 + 0];
    out[((size_t)b * DET_ + t) * 4 + 1] = topBox[src * 4 + 1];
    out[((size_t)b * DET_ + t) * 4 + 2] = topBox[src * 4 + 2];
    out[((size_t)b * DET_ + t) * 4 + 3] = topBox[src * 4 + 3];
    out[B_ * DET_ * 4 + (size_t)b * DET_ + t] = score;
    out[B_ * DET_ * 4 + B_ * DET_ + (size_t)b * DET_ + t] = (float)topLabel[src];
  }
}

extern "C" void kernel_launch(void* const* d_in, const int* in_sizes, int n_in,
                              void* d_out, int out_size, void* d_ws, size_t ws_size,
                              hipStream_t stream) {
  const float* label_pre = (const float*)d_in[0];
  const float* bbox_pre = (const float*)d_in[1];
  const float* props = (const float*)d_in[2];
  float* out = (float*)d_out;

  char* ws = (char*)d_ws;
  size_t off = 0;
  auto alloc = [&](size_t bytes) -> void* {
    void* p = ws + off;
    off = (off + bytes + 255) & ~(size_t)255;
    return p;
  };

  uint32_t* keys = (uint32_t*)alloc((size_t)B_ * NC_ * 4);
  float2* md = (float2*)alloc((size_t)B_ * N_ * 8);
  uint32_t* blockHist = (uint32_t*)alloc((size_t)B_ * IB_ * CB_ * 4);  // fully written
  // ---- zero-init region (one memset): fineHist, cnt, cand ----
  size_t zero_begin = off;
  uint32_t* fineHist = (uint32_t*)alloc((size_t)B_ * FB_ * 4);
  uint32_t* cnt = (uint32_t*)alloc((size_t)B_ * SLOTS_ * 16 * 4);
  u64* cand = (u64*)alloc((size_t)B_ * CAND_ * 8);
  size_t zero_end = off;
  // ------------------------------------------------------------
  uint32_t* thr = (uint32_t*)alloc((size_t)B_ * 4);
  int* coarse = (int*)alloc((size_t)B_ * 4);
  uint32_t* tailA = (uint32_t*)alloc((size_t)B_ * 4);
  float* topScore = (float*)alloc((size_t)B_ * KP_ * 4);
  int* topLabel = (int*)alloc((size_t)B_ * KP_ * 4);
  float* topBox = (float*)alloc((size_t)B_ * KP_ * 16);
  float* nmsBox = (float*)alloc((size_t)B_ * KP_ * 16);
  u64* sup = (u64*)alloc((size_t)B_ * KP_ * NW_ * 8);
  float* finalScore = (float*)alloc((size_t)B_ * KP_ * 4);

  if (off > ws_size) return;  // workspace too small -> fail visibly

  hipMemsetAsync(ws + zero_begin, 0, zero_end - zero_begin, stream);

  k_softmax<<<B_ * N_ / 64, 64, 0, stream>>>(label_pre, md);
  k_scores2<<<B_ * IB_, 256, 0, stream>>>(label_pre, bbox_pre, props, md, keys, blockHist);
  k_select<<<B_, 64, 0, stream>>>(blockHist, coarse, tailA, thr);
  k_refine<<<(B_ * NC_ / 4 + 255) / 256, 256, 0, stream>>>(keys, coarse, fineHist);
  k_select2<<<B_, 64, 0, stream>>>(fineHist, coarse, tailA, thr);
  k_compact<<<(B_ * NC_ / 4 + 255) / 256, 256, 0, stream>>>(keys, thr, cnt, cand);
  k_sort_topk<<<B_, 1024, 0, stream>>>(cand, bbox_pre, props,
                                       topScore, topLabel, topBox, nmsBox);
  k_supmat<<<B_ * 1024, 64, 0, stream>>>(nmsBox, sup);
  k_nms_scan<<<B_, 64, 0, stream>>>(sup, topScore, finalScore);
  k_final<<<B_, 1024, 0, stream>>>(finalScore, topBox, topLabel, out);
}

// Round 6
// 364.456 us; speedup vs baseline: 2.9404x; 1.0727x over previous
//
#include <hip/hip_runtime.h>
#include <stdint.h>

#define B_ 8
#define N_ 4000
#define C_ 80
#define NC_ (N_ * C_)          // 320000 candidates per image
#define KP_ 2048               // K_PRE
#define CAND_ 4096             // compaction capacity = SLOTS_*SLOTCAP_
#define SLOTS_ 32
#define SLOTCAP_ 128
#define DET_ 100
#define NW_ 32                 // u64 words per NMS row (2048 bits)
#define CLIP_ 4.135166556742356f

#define PB_ 16                 // proposals per k_scores2 block
#define IB_ (N_ / PB_)         // 250 blocks per image
#define CB_ 64                 // coarse bins ((key>>20)-960 in [2,55] for score in (0.01,1))
#define FB_ 128                // fine bins (key>>13 & 127)

typedef unsigned long long u64;

__device__ __forceinline__ void decode4(const float4 pr, const float4 d,
                                        float& x1, float& y1, float& x2, float& y2) {
  float w = pr.z - pr.x, h = pr.w - pr.y;
  float cx = pr.x + 0.5f * w, cy = pr.y + 0.5f * h;
  float dx = d.x / 10.0f, dy = d.y / 10.0f;
  float dw = fminf(d.z / 5.0f, CLIP_), dh = fminf(d.w / 5.0f, CLIP_);
  float pcx = dx * w + cx, pcy = dy * h + cy;
  float pw = expf(dw) * w, ph = expf(dh) * h;
  x1 = pcx - 0.5f * pw; y1 = pcy - 0.5f * ph;
  x2 = pcx + 0.5f * pw; y2 = pcy + 0.5f * ph;
}

// K0: per-proposal softmax max+denom (sequential sum order preserved bit-exactly).
__global__ __launch_bounds__(64) void k_softmax(const float* __restrict__ logits,
                                                float2* __restrict__ md) {
  __shared__ float lds[64 * 81];
  int blk = blockIdx.x, t = threadIdx.x;
  const float4* src = (const float4*)(logits + (size_t)blk * 64 * 81);
  for (int k = t; k < 64 * 81 / 4; k += 64) ((float4*)lds)[k] = src[k];
  __syncthreads();
  const float* lp = lds + t * 81;
  float m = lp[0];
  for (int i = 1; i <= C_; ++i) m = fmaxf(m, lp[i]);
  float denom = 0.f;
  for (int i = 0; i <= C_; ++i) denom += expf(lp[i] - m);
  md[blk * 64 + t] = make_float2(m, denom);
}

// K1: scores + validity keys + per-block coarse histogram (no global atomics).
__global__ __launch_bounds__(256) void k_scores2(const float* __restrict__ logits,
                                                 const float* __restrict__ bbox,
                                                 const float* __restrict__ props,
                                                 const float2* __restrict__ md,
                                                 uint32_t* __restrict__ keys,
                                                 uint32_t* __restrict__ blockHist) {
  __shared__ uint32_t hcnt[CB_];
  int blk = blockIdx.x;                 // 0 .. B_*IB_-1
  int b = blk / IB_, lb = blk - b * IB_;
  int p0 = lb * PB_;
  int t = threadIdx.x;
  if (t < CB_) hcnt[t] = 0;
  __syncthreads();
  const float4* props4 = (const float4*)props;
  const float4* bbox4 = (const float4*)bbox;
#pragma unroll
  for (int iter = 0; iter < PB_ * C_ / 256; ++iter) {   // 5 iters
    int e = iter * 256 + t;             // 0..1279
    int pp = e / C_, c = e - pp * C_;
    int p = b * N_ + p0 + pp;
    float lv = logits[(size_t)p * (C_ + 1) + c + 1];
    float2 md2 = md[p];
    float score = expf(lv - md2.x) / md2.y;
    uint32_t key = 0;
    if (score > 0.01f) {
      float4 pr4 = props4[p];
      float4 d = bbox4[(size_t)p * (C_ + 1) + c + 1];
      float x1, y1, x2, y2;
      decode4(pr4, d, x1, y1, x2, y2);
      float area = (y2 - y1) * (x2 - x1);
      if (area > 0.1f) {
        key = __float_as_uint(score);
        atomicAdd(&hcnt[(key >> 20) - 960], 1u);   // LDS atomic
      } else key = 0;
    }
    keys[(size_t)p * C_ + c] = key;
  }
  __syncthreads();
  if (t < CB_) blockHist[(size_t)blk * CB_ + t] = hcnt[t];
}

// K2: coarse select — one wave per image: reduce block hists + shfl suffix scan.
__global__ __launch_bounds__(64) void k_select(const uint32_t* __restrict__ blockHist,
                                               int* __restrict__ coarse,
                                               uint32_t* __restrict__ tailA,
                                               uint32_t* __restrict__ thr) {
  int b = blockIdx.x, lane = threadIdx.x;
  const uint32_t* hb = blockHist + (size_t)b * IB_ * CB_;
  uint32_t s = 0;
  for (int k = 0; k < IB_; ++k) s += hb[(size_t)k * CB_ + lane];
  uint32_t v = s;
#pragma unroll
  for (int d = 1; d < 64; d <<= 1) {
    uint32_t o = __shfl_down(v, d);
    v += (lane + d < 64) ? o : 0;
  }
  uint32_t nxt = __shfl_down(v, 1);
  if (lane == 63) nxt = 0;
  uint32_t total = __shfl(v, 0);
  if (total < KP_) {
    if (lane == 0) { coarse[b] = -1; thr[b] = 1u; }
    return;
  }
  if (v >= KP_ && nxt < KP_) { coarse[b] = lane; tailA[b] = nxt; }
}

// K2b: fine histogram of keys inside the coarse bin (few thousand atomics total)
__global__ void k_refine(const uint32_t* __restrict__ keys, const int* __restrict__ coarse,
                         uint32_t* __restrict__ fineHist) {
  int t = blockIdx.x * blockDim.x + threadIdx.x;   // B_*NC_/4 threads
  if (t >= B_ * NC_ / 4) return;
  uint4 k4 = ((const uint4*)keys)[t];
  int b = t / (NC_ / 4);
  int cb = coarse[b];
  if (cb < 0) return;
  uint32_t want = (uint32_t)(cb + 960);
  uint32_t kv[4] = {k4.x, k4.y, k4.z, k4.w};
#pragma unroll
  for (int q = 0; q < 4; ++q)
    if ((kv[q] >> 20) == want)
      atomicAdd(&fineHist[b * FB_ + ((kv[q] >> 13) & (FB_ - 1))], 1u);
}

// K2c: fine select — one wave per image over 128 fine bins (2 per lane)
__global__ __launch_bounds__(64) void k_select2(const uint32_t* __restrict__ fineHist,
                                                const int* __restrict__ coarse,
                                                const uint32_t* __restrict__ tailA,
                                                uint32_t* __restrict__ thr) {
  int b = blockIdx.x, lane = threadIdx.x;
  int cb = coarse[b];
  if (cb < 0) return;                    // thr already set by k_select
  uint32_t f0 = fineHist[b * FB_ + 2 * lane];
  uint32_t f1 = fineHist[b * FB_ + 2 * lane + 1];
  uint32_t ps = f0 + f1;
  uint32_t v = ps;
#pragma unroll
  for (int d = 1; d < 64; d <<= 1) {
    uint32_t o = __shfl_down(v, d);
    v += (lane + d < 64) ? o : 0;
  }
  uint32_t nxt = __shfl_down(v, 1);
  if (lane == 63) nxt = 0;
  uint32_t tail = tailA[b];
  uint32_t S0 = v;              // S_fine(2*lane)
  uint32_t S1 = nxt + f1;       // S_fine(2*lane+1)
  bool c0 = (tail + S0 >= KP_);
  bool c1 = (tail + S1 >= KP_);
  bool cNext = (tail + nxt >= KP_);   // cond(2*lane+2)
  int ans = -1;
  if (c0 && !c1) ans = 2 * lane;
  if (c1 && !cNext) ans = 2 * lane + 1;
  if (ans >= 0)
    thr[b] = ((uint32_t)(cb + 960) << 20) | ((uint32_t)ans << 13);
}

// K3: compact survivors into 32 slots/image; slot counters on distinct 64B lines.
__global__ void k_compact(const uint32_t* __restrict__ keys, const uint32_t* __restrict__ thr,
                          uint32_t* __restrict__ cnt, u64* __restrict__ cand) {
  int t = blockIdx.x * blockDim.x + threadIdx.x;   // B_*NC_/4 threads
  if (t >= B_ * NC_ / 4) return;
  uint4 k4 = ((const uint4*)keys)[t];
  int b = t / (NC_ / 4);
  int ti = t - b * (NC_ / 4);
  int slot = (ti >> 4) & (SLOTS_ - 1);
  uint32_t thrb = thr[b];
  uint32_t kv[4] = {k4.x, k4.y, k4.z, k4.w};
  int ns = 0;
#pragma unroll
  for (int q = 0; q < 4; ++q) ns += (kv[q] >= thrb) ? 1 : 0;
  if (ns == 0) return;
  uint32_t pos = atomicAdd(&cnt[(b * SLOTS_ + slot) * 16], (uint32_t)ns);
  u64* seg = cand + (size_t)b * CAND_ + slot * SLOTCAP_;
  uint32_t baseIdx = (uint32_t)(ti * 4);
#pragma unroll
  for (int q = 0; q < 4; ++q) {
    if (kv[q] >= thrb) {
      if (pos < SLOTCAP_)
        seg[pos] = ((u64)kv[q] << 32) | (uint32_t)(~(baseIdx + q));
      ++pos;
    }
  }
}

// K4: per-image bitonic sort (4096, LDS) -> top 2048, re-decode + NMS offset
__global__ __launch_bounds__(1024) void k_sort_topk(
    const u64* __restrict__ cand,
    const float* __restrict__ bbox, const float* __restrict__ props,
    float* __restrict__ topScore, int* __restrict__ topLabel,
    float* __restrict__ topBox, float* __restrict__ nmsBox) {
  __shared__ u64 sh[CAND_];
  int b = blockIdx.x, t = threadIdx.x;
  for (int i = t; i < CAND_; i += 1024)
    sh[i] = cand[(size_t)b * CAND_ + i];          // zeros where unfilled (memset)
  __syncthreads();
  for (unsigned size = 2; size <= CAND_; size <<= 1) {
    for (unsigned stride = size >> 1; stride; stride >>= 1) {
      for (unsigned i = t; i < CAND_; i += 1024) {
        unsigned j = i ^ stride;
        if (j > i) {
          bool desc = ((i & size) == 0);
          u64 a = sh[i], bb2 = sh[j];
          bool sw = desc ? (a < bb2) : (a > bb2);
          if (sw) { sh[i] = bb2; sh[j] = a; }
        }
      }
      __syncthreads();
    }
  }
  for (int k = t; k < KP_; k += 1024) {
    u64 key = sh[k];
    size_t o = (size_t)b * KP_ + k;
    if (key == 0ull) {
      topScore[o] = -1.0f;
      topLabel[o] = 0;
      for (int j2 = 0; j2 < 4; ++j2) { topBox[o * 4 + j2] = 0.f; nmsBox[o * 4 + j2] = 0.f; }
      continue;
    }
    uint32_t sbits = (uint32_t)(key >> 32);
    uint32_t idx = ~((uint32_t)key);
    int n = idx / C_, c = idx % C_;
    float4 pr4 = ((const float4*)props)[(size_t)b * N_ + n];
    float4 d = ((const float4*)(bbox + ((size_t)b * N_ + n) * ((C_ + 1) * 4)))[c + 1];
    float x1, y1, x2, y2;
    decode4(pr4, d, x1, y1, x2, y2);
    float off = (float)(c + 1) * 4096.0f;
    topScore[o] = __uint_as_float(sbits);
    topLabel[o] = c + 1;
    topBox[o * 4 + 0] = x1; topBox[o * 4 + 1] = y1;
    topBox[o * 4 + 2] = x2; topBox[o * 4 + 3] = y2;
    nmsBox[o * 4 + 0] = x1 + off; nmsBox[o * 4 + 1] = y1 + off;
    nmsBox[o * 4 + 2] = x2 + off; nmsBox[o * 4 + 3] = y2 + off;
  }
}

// K5: suppression bitmatrix, 64x64 tiles, j-boxes in LDS (broadcast reads).
// Only upper-triangle tiles (tj >= ti) are written; downstream never reads w < chunk.
__global__ __launch_bounds__(64) void k_supmat(const float* __restrict__ nmsBox,
                                               u64* __restrict__ sup) {
  int blk = blockIdx.x;
  int b = blk >> 10, rest = blk & 1023;
  int ti = rest >> 5, tj = rest & 31;
  if (tj < ti) return;                       // block-uniform early-out
  __shared__ float4 shj[64];
  int l = threadIdx.x;
  const float4* boxes = (const float4*)(nmsBox + (size_t)b * KP_ * 4);
  shj[l] = boxes[tj * 64 + l];
  int i = ti * 64 + l;
  float4 bi = boxes[i];
  float areai = fmaxf(bi.z - bi.x, 0.f) * fmaxf(bi.w - bi.y, 0.f);
  __syncthreads();
  u64 bits = 0;
  for (int jj = 0; jj < 64; ++jj) {
    int j = tj * 64 + jj;
    if (j > i) {
      float4 bj = shj[jj];
      float areaj = fmaxf(bj.z - bj.x, 0.f) * fmaxf(bj.w - bj.y, 0.f);
      float ltx = fmaxf(bi.x, bj.x), lty = fmaxf(bi.y, bj.y);
      float rbx = fminf(bi.z, bj.z), rby = fminf(bi.w, bj.w);
      float iw = fmaxf(rbx - ltx, 0.f), ih = fmaxf(rby - lty, 0.f);
      float inter = iw * ih;
      float uni = areai + areaj - inter;
      float iou = inter / fmaxf(uni, 1e-9f);
      if (iou > 0.5f) bits |= (1ull << jj);
    }
  }
  sup[((size_t)b * KP_ + i) * NW_ + tj] = bits;
}

// K6: chunked greedy NMS, 256 threads/image.
// Phase-B loads (8/thread, coalesced) issue BEFORE wave 0's serial readlane
// chain, overlapping load latency with the dependent chain. `removed` lives in
// LDS; phase-B contributions merge via ds_or_b64.
__global__ __launch_bounds__(256) void k_nms_scan(const u64* __restrict__ sup,
                                                  const float* __restrict__ topScore,
                                                  float* __restrict__ finalScore) {
  __shared__ u64 lds_removed[NW_];
  __shared__ u64 lds_keep;
  __shared__ unsigned char initm[256];
  int b = blockIdx.x, t = threadIdx.x;
  int wave = t >> 6, lane = t & 63;
  int w = t & 31, g = t >> 5;              // word / row-group (8 rows each)
  const u64* base = sup + (size_t)b * KP_ * NW_;
  const float* ts = topScore + (size_t)b * KP_;
  // init keep0 mask: thread t covers scores [t*8, t*8+8), coalesced float4 x2
  float4 a0 = ((const float4*)ts)[t * 2];
  float4 a1 = ((const float4*)ts)[t * 2 + 1];
  float sv[8] = {a0.x, a0.y, a0.z, a0.w, a1.x, a1.y, a1.z, a1.w};
  {
    unsigned m = 0;
#pragma unroll
    for (int j = 0; j < 8; ++j) if (!(sv[j] > 0.f)) m |= 1u << j;
    initm[t] = (unsigned char)m;
  }
  __syncthreads();
  if (t < NW_) {
    u64 r = 0;
#pragma unroll
    for (int k = 0; k < 8; ++k) r |= (u64)initm[t * 8 + k] << (8 * k);
    lds_removed[t] = r;
  }
  __syncthreads();
  // wave 0 prefetches diag of chunk 0 (lane i holds sup[0*64+i][0])
  u64 diag = (wave == 0) ? base[(size_t)lane * NW_] : 0ull;
  for (int c = 0; c < NW_; ++c) {
    // ---- issue phase-B loads for chunk c (independent of keep) ----
    u64 r0 = 0, r1 = 0, r2 = 0, r3 = 0, r4 = 0, r5 = 0, r6 = 0, r7 = 0;
    if (w > c) {
      const u64* rowb = base + ((size_t)c * 64 + g * 8) * NW_ + w;
      r0 = rowb[0 * NW_]; r1 = rowb[1 * NW_]; r2 = rowb[2 * NW_]; r3 = rowb[3 * NW_];
      r4 = rowb[4 * NW_]; r5 = rowb[5 * NW_]; r6 = rowb[6 * NW_]; r7 = rowb[7 * NW_];
    }
    // ---- wave 0: serial greedy within chunk c ----
    if (wave == 0) {
      u64 diag_cur = diag;
      if (c + 1 < NW_)
        diag = base[(size_t)((c + 1) * 64 + lane) * NW_ + (c + 1)];
      u64 rm = lds_removed[c];
      unsigned dlo = (unsigned)diag_cur, dhi = (unsigned)(diag_cur >> 32);
#pragma unroll
      for (int i = 0; i < 64; ++i) {
        u64 di = ((u64)__builtin_amdgcn_readlane(dhi, i) << 32) |
                 (u64)__builtin_amdgcn_readlane(dlo, i);
        if (!((rm >> i) & 1ull)) rm |= di;
      }
      if (lane == 0) { lds_removed[c] = rm; lds_keep = ~rm; }
    }
    __syncthreads();
    // ---- all threads: masked OR of kept rows into word w (> c) ----
    if (w > c) {
      u64 keep = lds_keep;
      u64 acc = 0;
      acc |= ((keep >> (g * 8 + 0)) & 1ull) ? r0 : 0ull;
      acc |= ((keep >> (g * 8 + 1)) & 1ull) ? r1 : 0ull;
      acc |= ((keep >> (g * 8 + 2)) & 1ull) ? r2 : 0ull;
      acc |= ((keep >> (g * 8 + 3)) & 1ull) ? r3 : 0ull;
      acc |= ((keep >> (g * 8 + 4)) & 1ull) ? r4 : 0ull;
      acc |= ((keep >> (g * 8 + 5)) & 1ull) ? r5 : 0ull;
      acc |= ((keep >> (g * 8 + 6)) & 1ull) ? r6 : 0ull;
      acc |= ((keep >> (g * 8 + 7)) & 1ull) ? r7 : 0ull;
      if (acc) atomicOr(&lds_removed[w], acc);
    }
    __syncthreads();
  }
  // write finalScore: thread t covers [t*8, t*8+8), coalesced float4 x2
  {
    u64 wd = lds_removed[t >> 3];
    unsigned mbyte = (unsigned)((wd >> ((t & 7) * 8)) & 0xffu);
#pragma unroll
    for (int j = 0; j < 8; ++j) if (mbyte & (1u << j)) sv[j] = -1.0f;
    float4* o = (float4*)(finalScore + (size_t)b * KP_) + t * 2;
    o[0] = make_float4(sv[0], sv[1], sv[2], sv[3]);
    o[1] = make_float4(sv[4], sv[5], sv[6], sv[7]);
  }
}

// K7: final stable top-100 + output
__global__ __launch_bounds__(1024) void k_final(
    const float* __restrict__ finalScore, const float* __restrict__ topBox,
    const int* __restrict__ topLabel, float* __restrict__ out) {
  __shared__ u64 sh[KP_];
  int b = blockIdx.x, t = threadIdx.x;
  for (int i = t; i < KP_; i += 1024) {
    float f = finalScore[(size_t)b * KP_ + i];
    uint32_t u = __float_as_uint(f);
    u = (u & 0x80000000u) ? ~u : (u | 0x80000000u);  // total-order transform
    sh[i] = ((u64)u << 32) | (uint32_t)(~(uint32_t)i);
  }
  __syncthreads();
  for (unsigned size = 2; size <= KP_; size <<= 1) {
    for (unsigned stride = size >> 1; stride; stride >>= 1) {
      for (unsigned i = t; i < KP_; i += 1024) {
        unsigned j = i ^ stride;
        if (j > i) {
          bool desc = ((i & size) == 0);
          u64 a = sh[i], bb2 = sh[j];
          bool sw = desc ? (a < bb2) : (a > bb2);
          if (sw) { sh[i] = bb2; sh[j] = a; }
        }
      }
      __syncthreads();
    }
  }
  if (t < DET_) {
    u64 key = sh[t];
    uint32_t k = ~((uint32_t)key);
    size_t src = (size_t)b * KP_ + k;
    float score = finalScore[src];
    out[((size_t)b * DET_ + t) * 4 + 0] = topBox[src * 4 + 0];
    out[((size_t)b * DET_ + t) * 4 + 1] = topBox[src * 4 + 1];
    out[((size_t)b * DET_ + t) * 4 + 2] = topBox[src * 4 + 2];
    out[((size_t)b * DET_ + t) * 4 + 3] = topBox[src * 4 + 3];
    out[B_ * DET_ * 4 + (size_t)b * DET_ + t] = score;
    out[B_ * DET_ * 4 + B_ * DET_ + (size_t)b * DET_ + t] = (float)topLabel[src];
  }
}

extern "C" void kernel_launch(void* const* d_in, const int* in_sizes, int n_in,
                              void* d_out, int out_size, void* d_ws, size_t ws_size,
                              hipStream_t stream) {
  const float* label_pre = (const float*)d_in[0];
  const float* bbox_pre = (const float*)d_in[1];
  const float* props = (const float*)d_in[2];
  float* out = (float*)d_out;

  char* ws = (char*)d_ws;
  size_t off = 0;
  auto alloc = [&](size_t bytes) -> void* {
    void* p = ws + off;
    off = (off + bytes + 255) & ~(size_t)255;
    return p;
  };

  uint32_t* keys = (uint32_t*)alloc((size_t)B_ * NC_ * 4);
  float2* md = (float2*)alloc((size_t)B_ * N_ * 8);
  uint32_t* blockHist = (uint32_t*)alloc((size_t)B_ * IB_ * CB_ * 4);  // fully written
  // ---- zero-init region (one memset): fineHist, cnt, cand ----
  size_t zero_begin = off;
  uint32_t* fineHist = (uint32_t*)alloc((size_t)B_ * FB_ * 4);
  uint32_t* cnt = (uint32_t*)alloc((size_t)B_ * SLOTS_ * 16 * 4);
  u64* cand = (u64*)alloc((size_t)B_ * CAND_ * 8);
  size_t zero_end = off;
  // ------------------------------------------------------------
  uint32_t* thr = (uint32_t*)alloc((size_t)B_ * 4);
  int* coarse = (int*)alloc((size_t)B_ * 4);
  uint32_t* tailA = (uint32_t*)alloc((size_t)B_ * 4);
  float* topScore = (float*)alloc((size_t)B_ * KP_ * 4);
  int* topLabel = (int*)alloc((size_t)B_ * KP_ * 4);
  float* topBox = (float*)alloc((size_t)B_ * KP_ * 16);
  float* nmsBox = (float*)alloc((size_t)B_ * KP_ * 16);
  u64* sup = (u64*)alloc((size_t)B_ * KP_ * NW_ * 8);
  float* finalScore = (float*)alloc((size_t)B_ * KP_ * 4);

  if (off > ws_size) return;  // workspace too small -> fail visibly

  hipMemsetAsync(ws + zero_begin, 0, zero_end - zero_begin, stream);

  k_softmax<<<B_ * N_ / 64, 64, 0, stream>>>(label_pre, md);
  k_scores2<<<B_ * IB_, 256, 0, stream>>>(label_pre, bbox_pre, props, md, keys, blockHist);
  k_select<<<B_, 64, 0, stream>>>(blockHist, coarse, tailA, thr);
  k_refine<<<(B_ * NC_ / 4 + 255) / 256, 256, 0, stream>>>(keys, coarse, fineHist);
  k_select2<<<B_, 64, 0, stream>>>(fineHist, coarse, tailA, thr);
  k_compact<<<(B_ * NC_ / 4 + 255) / 256, 256, 0, stream>>>(keys, thr, cnt, cand);
  k_sort_topk<<<B_, 1024, 0, stream>>>(cand, bbox_pre, props,
                                       topScore, topLabel, topBox, nmsBox);
  k_supmat<<<B_ * 1024, 64, 0, stream>>>(nmsBox, sup);
  k_nms_scan<<<B_, 256, 0, stream>>>(sup, topScore, finalScore);
  k_final<<<B_, 1024, 0, stream>>>(finalScore, topBox, topLabel, out);
}

// Round 7
// 321.626 us; speedup vs baseline: 3.3319x; 1.1332x over previous
//
#include <hip/hip_runtime.h>
#include <stdint.h>

#define B_ 8
#define N_ 4000
#define C_ 80
#define NC_ (N_ * C_)          // 320000 candidates per image
#define KP_ 2048               // K_PRE
#define CAND_ 4096             // compaction capacity = SLOTS_*SLOTCAP_
#define SLOTS_ 32
#define SLOTCAP_ 128
#define DET_ 100
#define NW_ 32                 // u64 words per NMS row (2048 bits)
#define CLIP_ 4.135166556742356f

#define PB_ 16                 // proposals per k_scores2 block
#define IB_ (N_ / PB_)         // 250 blocks per image
#define CB_ 64                 // coarse bins ((key>>20)-960 in [2,55] for score in (0.01,1))
#define FB_ 128                // fine bins (key>>13 & 127)

typedef unsigned long long u64;

__device__ __forceinline__ void decode4(const float4 pr, const float4 d,
                                        float& x1, float& y1, float& x2, float& y2) {
  float w = pr.z - pr.x, h = pr.w - pr.y;
  float cx = pr.x + 0.5f * w, cy = pr.y + 0.5f * h;
  float dx = d.x / 10.0f, dy = d.y / 10.0f;
  float dw = fminf(d.z / 5.0f, CLIP_), dh = fminf(d.w / 5.0f, CLIP_);
  float pcx = dx * w + cx, pcy = dy * h + cy;
  float pw = expf(dw) * w, ph = expf(dh) * h;
  x1 = pcx - 0.5f * pw; y1 = pcy - 0.5f * ph;
  x2 = pcx + 0.5f * pw; y2 = pcy + 0.5f * ph;
}

// K0: per-proposal softmax max+denom (sequential sum order preserved bit-exactly).
__global__ __launch_bounds__(64) void k_softmax(const float* __restrict__ logits,
                                                float2* __restrict__ md) {
  __shared__ float lds[64 * 81];
  int blk = blockIdx.x, t = threadIdx.x;
  const float4* src = (const float4*)(logits + (size_t)blk * 64 * 81);
  for (int k = t; k < 64 * 81 / 4; k += 64) ((float4*)lds)[k] = src[k];
  __syncthreads();
  const float* lp = lds + t * 81;
  float m = lp[0];
  for (int i = 1; i <= C_; ++i) m = fmaxf(m, lp[i]);
  float denom = 0.f;
  for (int i = 0; i <= C_; ++i) denom += expf(lp[i] - m);
  md[blk * 64 + t] = make_float2(m, denom);
}

// K1: scores + validity keys + per-block coarse histogram (no global atomics).
__global__ __launch_bounds__(256) void k_scores2(const float* __restrict__ logits,
                                                 const float* __restrict__ bbox,
                                                 const float* __restrict__ props,
                                                 const float2* __restrict__ md,
                                                 uint32_t* __restrict__ keys,
                                                 uint32_t* __restrict__ blockHist) {
  __shared__ uint32_t hcnt[CB_];
  int blk = blockIdx.x;                 // 0 .. B_*IB_-1
  int b = blk / IB_, lb = blk - b * IB_;
  int p0 = lb * PB_;
  int t = threadIdx.x;
  if (t < CB_) hcnt[t] = 0;
  __syncthreads();
  const float4* props4 = (const float4*)props;
  const float4* bbox4 = (const float4*)bbox;
#pragma unroll
  for (int iter = 0; iter < PB_ * C_ / 256; ++iter) {   // 5 iters
    int e = iter * 256 + t;             // 0..1279
    int pp = e / C_, c = e - pp * C_;
    int p = b * N_ + p0 + pp;
    float lv = logits[(size_t)p * (C_ + 1) + c + 1];
    float2 md2 = md[p];
    float score = expf(lv - md2.x) / md2.y;
    uint32_t key = 0;
    if (score > 0.01f) {
      float4 pr4 = props4[p];
      float4 d = bbox4[(size_t)p * (C_ + 1) + c + 1];
      float x1, y1, x2, y2;
      decode4(pr4, d, x1, y1, x2, y2);
      float area = (y2 - y1) * (x2 - x1);
      if (area > 0.1f) {
        key = __float_as_uint(score);
        atomicAdd(&hcnt[(key >> 20) - 960], 1u);   // LDS atomic
      } else key = 0;
    }
    keys[(size_t)p * C_ + c] = key;
  }
  __syncthreads();
  if (t < CB_) blockHist[(size_t)blk * CB_ + t] = hcnt[t];
}

// K2: coarse select — one wave per image: reduce block hists + shfl suffix scan.
__global__ __launch_bounds__(64) void k_select(const uint32_t* __restrict__ blockHist,
                                               int* __restrict__ coarse,
                                               uint32_t* __restrict__ tailA,
                                               uint32_t* __restrict__ thr) {
  int b = blockIdx.x, lane = threadIdx.x;
  const uint32_t* hb = blockHist + (size_t)b * IB_ * CB_;
  uint32_t s = 0;
  for (int k = 0; k < IB_; ++k) s += hb[(size_t)k * CB_ + lane];
  uint32_t v = s;
#pragma unroll
  for (int d = 1; d < 64; d <<= 1) {
    uint32_t o = __shfl_down(v, d);
    v += (lane + d < 64) ? o : 0;
  }
  uint32_t nxt = __shfl_down(v, 1);
  if (lane == 63) nxt = 0;
  uint32_t total = __shfl(v, 0);
  if (total < KP_) {
    if (lane == 0) { coarse[b] = -1; thr[b] = 1u; }
    return;
  }
  if (v >= KP_ && nxt < KP_) { coarse[b] = lane; tailA[b] = nxt; }
}

// K2b: fine histogram of keys inside the coarse bin (few thousand atomics total)
__global__ void k_refine(const uint32_t* __restrict__ keys, const int* __restrict__ coarse,
                         uint32_t* __restrict__ fineHist) {
  int t = blockIdx.x * blockDim.x + threadIdx.x;   // B_*NC_/4 threads
  if (t >= B_ * NC_ / 4) return;
  uint4 k4 = ((const uint4*)keys)[t];
  int b = t / (NC_ / 4);
  int cb = coarse[b];
  if (cb < 0) return;
  uint32_t want = (uint32_t)(cb + 960);
  uint32_t kv[4] = {k4.x, k4.y, k4.z, k4.w};
#pragma unroll
  for (int q = 0; q < 4; ++q)
    if ((kv[q] >> 20) == want)
      atomicAdd(&fineHist[b * FB_ + ((kv[q] >> 13) & (FB_ - 1))], 1u);
}

// K2c: fine select — one wave per image over 128 fine bins (2 per lane)
__global__ __launch_bounds__(64) void k_select2(const uint32_t* __restrict__ fineHist,
                                                const int* __restrict__ coarse,
                                                const uint32_t* __restrict__ tailA,
                                                uint32_t* __restrict__ thr) {
  int b = blockIdx.x, lane = threadIdx.x;
  int cb = coarse[b];
  if (cb < 0) return;                    // thr already set by k_select
  uint32_t f0 = fineHist[b * FB_ + 2 * lane];
  uint32_t f1 = fineHist[b * FB_ + 2 * lane + 1];
  uint32_t ps = f0 + f1;
  uint32_t v = ps;
#pragma unroll
  for (int d = 1; d < 64; d <<= 1) {
    uint32_t o = __shfl_down(v, d);
    v += (lane + d < 64) ? o : 0;
  }
  uint32_t nxt = __shfl_down(v, 1);
  if (lane == 63) nxt = 0;
  uint32_t tail = tailA[b];
  uint32_t S0 = v;              // S_fine(2*lane)
  uint32_t S1 = nxt + f1;       // S_fine(2*lane+1)
  bool c0 = (tail + S0 >= KP_);
  bool c1 = (tail + S1 >= KP_);
  bool cNext = (tail + nxt >= KP_);   // cond(2*lane+2)
  int ans = -1;
  if (c0 && !c1) ans = 2 * lane;
  if (c1 && !cNext) ans = 2 * lane + 1;
  if (ans >= 0)
    thr[b] = ((uint32_t)(cb + 960) << 20) | ((uint32_t)ans << 13);
}

// K3: compact survivors into 32 slots/image; slot counters on distinct 64B lines.
__global__ void k_compact(const uint32_t* __restrict__ keys, const uint32_t* __restrict__ thr,
                          uint32_t* __restrict__ cnt, u64* __restrict__ cand) {
  int t = blockIdx.x * blockDim.x + threadIdx.x;   // B_*NC_/4 threads
  if (t >= B_ * NC_ / 4) return;
  uint4 k4 = ((const uint4*)keys)[t];
  int b = t / (NC_ / 4);
  int ti = t - b * (NC_ / 4);
  int slot = (ti >> 4) & (SLOTS_ - 1);
  uint32_t thrb = thr[b];
  uint32_t kv[4] = {k4.x, k4.y, k4.z, k4.w};
  int ns = 0;
#pragma unroll
  for (int q = 0; q < 4; ++q) ns += (kv[q] >= thrb) ? 1 : 0;
  if (ns == 0) return;
  uint32_t pos = atomicAdd(&cnt[(b * SLOTS_ + slot) * 16], (uint32_t)ns);
  u64* seg = cand + (size_t)b * CAND_ + slot * SLOTCAP_;
  uint32_t baseIdx = (uint32_t)(ti * 4);
#pragma unroll
  for (int q = 0; q < 4; ++q) {
    if (kv[q] >= thrb) {
      if (pos < SLOTCAP_)
        seg[pos] = ((u64)kv[q] << 32) | (uint32_t)(~(baseIdx + q));
      ++pos;
    }
  }
}

// K4: per-image bitonic sort (4096, LDS) -> top 2048, re-decode + NMS offset
__global__ __launch_bounds__(1024) void k_sort_topk(
    const u64* __restrict__ cand,
    const float* __restrict__ bbox, const float* __restrict__ props,
    float* __restrict__ topScore, int* __restrict__ topLabel,
    float* __restrict__ topBox, float* __restrict__ nmsBox) {
  __shared__ u64 sh[CAND_];
  int b = blockIdx.x, t = threadIdx.x;
  for (int i = t; i < CAND_; i += 1024)
    sh[i] = cand[(size_t)b * CAND_ + i];          // zeros where unfilled (memset)
  __syncthreads();
  for (unsigned size = 2; size <= CAND_; size <<= 1) {
    for (unsigned stride = size >> 1; stride; stride >>= 1) {
      for (unsigned i = t; i < CAND_; i += 1024) {
        unsigned j = i ^ stride;
        if (j > i) {
          bool desc = ((i & size) == 0);
          u64 a = sh[i], bb2 = sh[j];
          bool sw = desc ? (a < bb2) : (a > bb2);
          if (sw) { sh[i] = bb2; sh[j] = a; }
        }
      }
      __syncthreads();
    }
  }
  for (int k = t; k < KP_; k += 1024) {
    u64 key = sh[k];
    size_t o = (size_t)b * KP_ + k;
    if (key == 0ull) {
      topScore[o] = -1.0f;
      topLabel[o] = 0;
      for (int j2 = 0; j2 < 4; ++j2) { topBox[o * 4 + j2] = 0.f; nmsBox[o * 4 + j2] = 0.f; }
      continue;
    }
    uint32_t sbits = (uint32_t)(key >> 32);
    uint32_t idx = ~((uint32_t)key);
    int n = idx / C_, c = idx % C_;
    float4 pr4 = ((const float4*)props)[(size_t)b * N_ + n];
    float4 d = ((const float4*)(bbox + ((size_t)b * N_ + n) * ((C_ + 1) * 4)))[c + 1];
    float x1, y1, x2, y2;
    decode4(pr4, d, x1, y1, x2, y2);
    float off = (float)(c + 1) * 4096.0f;
    topScore[o] = __uint_as_float(sbits);
    topLabel[o] = c + 1;
    topBox[o * 4 + 0] = x1; topBox[o * 4 + 1] = y1;
    topBox[o * 4 + 2] = x2; topBox[o * 4 + 3] = y2;
    nmsBox[o * 4 + 0] = x1 + off; nmsBox[o * 4 + 1] = y1 + off;
    nmsBox[o * 4 + 2] = x2 + off; nmsBox[o * 4 + 3] = y2 + off;
  }
}

// K5: suppression bitmatrix, 64x64 tiles, j-boxes in LDS (broadcast reads).
// Only upper-triangle tiles (tj >= ti) are written; downstream never reads w < chunk.
__global__ __launch_bounds__(64) void k_supmat(const float* __restrict__ nmsBox,
                                               u64* __restrict__ sup) {
  int blk = blockIdx.x;
  int b = blk >> 10, rest = blk & 1023;
  int ti = rest >> 5, tj = rest & 31;
  if (tj < ti) return;                       // block-uniform early-out
  __shared__ float4 shj[64];
  int l = threadIdx.x;
  const float4* boxes = (const float4*)(nmsBox + (size_t)b * KP_ * 4);
  shj[l] = boxes[tj * 64 + l];
  int i = ti * 64 + l;
  float4 bi = boxes[i];
  float areai = fmaxf(bi.z - bi.x, 0.f) * fmaxf(bi.w - bi.y, 0.f);
  __syncthreads();
  u64 bits = 0;
  for (int jj = 0; jj < 64; ++jj) {
    int j = tj * 64 + jj;
    if (j > i) {
      float4 bj = shj[jj];
      float areaj = fmaxf(bj.z - bj.x, 0.f) * fmaxf(bj.w - bj.y, 0.f);
      float ltx = fmaxf(bi.x, bj.x), lty = fmaxf(bi.y, bj.y);
      float rbx = fminf(bi.z, bj.z), rby = fminf(bi.w, bj.w);
      float iw = fmaxf(rbx - ltx, 0.f), ih = fmaxf(rby - lty, 0.f);
      float inter = iw * ih;
      float uni = areai + areaj - inter;
      float iou = inter / fmaxf(uni, 1e-9f);
      if (iou > 0.5f) bits |= (1ull << jj);
    }
  }
  sup[((size_t)b * KP_ + i) * NW_ + tj] = bits;
}

// K6: single-wave chunked greedy NMS, barrier-free, register-resident.
// Lane l (h=l>>5, w=l&31) holds word w of rows h*32+k (k=0..31) of the current
// chunk in regs (double-buffered; coalesced loads for chunk c+1 overlap chunk
// c's compute). Phase A: 64-step greedy chain via readlane on the diag words.
// Phase B: 32 masked register-ORs + shfl_xor merge. Words < c of chunk-c rows
// are never written by k_supmat (upper-triangle only) -> guard l >= c.
__global__ __launch_bounds__(64) void k_nms_scan(const u64* __restrict__ sup,
                                                 const float* __restrict__ topScore,
                                                 float* __restrict__ finalScore) {
  int b = blockIdx.x, l = threadIdx.x;
  int h = l >> 5, w = l & 31;
  const u64* base = sup + (size_t)b * KP_ * NW_;
  const float* ts = topScore + (size_t)b * KP_;
  // per-lane scores: items [32*l, 32*l+32)
  float4 sv4[8];
#pragma unroll
  for (int j = 0; j < 8; ++j) sv4[j] = ((const float4*)ts)[l * 8 + j];
  unsigned m32 = 0;
#pragma unroll
  for (int j = 0; j < 8; ++j) {
    if (!(sv4[j].x > 0.f)) m32 |= 1u << (4 * j + 0);
    if (!(sv4[j].y > 0.f)) m32 |= 1u << (4 * j + 1);
    if (!(sv4[j].z > 0.f)) m32 |= 1u << (4 * j + 2);
    if (!(sv4[j].w > 0.f)) m32 |= 1u << (4 * j + 3);
  }
  // removed word w (meaningful on lanes 0-31): bits from lanes 2w, 2w+1
  u64 removed = ((u64)__shfl(m32, 2 * w + 1) << 32) | (u64)__shfl(m32, 2 * w);

  u64 ra[32], rb[32];
  auto loadc = [&](u64* dst, int c) {
    const u64* p = base + ((size_t)c * 64 + h * 32) * NW_ + w;
#pragma unroll
    for (int k = 0; k < 32; ++k) dst[k] = p[(size_t)k * NW_];
  };
  auto chunk = [&](u64* cur, int c) {
    u64 rm = __shfl(removed, c);
    unsigned rml = (unsigned)rm, rmh = (unsigned)(rm >> 32);
#pragma unroll
    for (int k = 0; k < 32; ++k) {                 // rows c*64+k (held by lane c)
      unsigned dlo = __builtin_amdgcn_readlane((unsigned)cur[k], c);
      unsigned dhi = __builtin_amdgcn_readlane((unsigned)(cur[k] >> 32), c);
      if (!((rml >> k) & 1u)) { rml |= dlo; rmh |= dhi; }
    }
#pragma unroll
    for (int k = 0; k < 32; ++k) {                 // rows c*64+32+k (lane 32+c)
      unsigned dlo = __builtin_amdgcn_readlane((unsigned)cur[k], 32 + c);
      unsigned dhi = __builtin_amdgcn_readlane((unsigned)(cur[k] >> 32), 32 + c);
      if (!((rmh >> k) & 1u)) { rml |= dlo; rmh |= dhi; }
    }
    unsigned kmask = h ? ~rmh : ~rml;              // keep bits for this lane's rows
    u64 acc = 0;
#pragma unroll
    for (int k = 0; k < 32; ++k)
      acc |= ((kmask >> k) & 1u) ? cur[k] : 0ull;
    acc |= __shfl_xor(acc, 32);                    // merge halves
    if (l < 32 && l >= c) removed |= acc;          // only valid (written) words
  };

  loadc(ra, 0);
  for (int c = 0; c < NW_; c += 2) {
    if (c + 1 < NW_) loadc(rb, c + 1);
    chunk(ra, c);
    if (c + 2 < NW_) loadc(ra, c + 2);
    if (c + 1 < NW_) chunk(rb, c + 1);
  }
  // apply: item 32l+j2 -> word l>>1, bit 32*(l&1)+j2
  u64 wd = __shfl(removed, l >> 1);
  unsigned mask = (unsigned)(wd >> (32 * (l & 1)));
#pragma unroll
  for (int j = 0; j < 8; ++j) {
    if (mask & (1u << (4 * j + 0))) sv4[j].x = -1.0f;
    if (mask & (1u << (4 * j + 1))) sv4[j].y = -1.0f;
    if (mask & (1u << (4 * j + 2))) sv4[j].z = -1.0f;
    if (mask & (1u << (4 * j + 3))) sv4[j].w = -1.0f;
  }
  float4* fo = (float4*)(finalScore + (size_t)b * KP_);
#pragma unroll
  for (int j = 0; j < 8; ++j) fo[l * 8 + j] = sv4[j];
}

// K7: final stable top-100 + output
__global__ __launch_bounds__(1024) void k_final(
    const float* __restrict__ finalScore, const float* __restrict__ topBox,
    const int* __restrict__ topLabel, float* __restrict__ out) {
  __shared__ u64 sh[KP_];
  int b = blockIdx.x, t = threadIdx.x;
  for (int i = t; i < KP_; i += 1024) {
    float f = finalScore[(size_t)b * KP_ + i];
    uint32_t u = __float_as_uint(f);
    u = (u & 0x80000000u) ? ~u : (u | 0x80000000u);  // total-order transform
    sh[i] = ((u64)u << 32) | (uint32_t)(~(uint32_t)i);
  }
  __syncthreads();
  for (unsigned size = 2; size <= KP_; size <<= 1) {
    for (unsigned stride = size >> 1; stride; stride >>= 1) {
      for (unsigned i = t; i < KP_; i += 1024) {
        unsigned j = i ^ stride;
        if (j > i) {
          bool desc = ((i & size) == 0);
          u64 a = sh[i], bb2 = sh[j];
          bool sw = desc ? (a < bb2) : (a > bb2);
          if (sw) { sh[i] = bb2; sh[j] = a; }
        }
      }
      __syncthreads();
    }
  }
  if (t < DET_) {
    u64 key = sh[t];
    uint32_t k = ~((uint32_t)key);
    size_t src = (size_t)b * KP_ + k;
    float score = finalScore[src];
    out[((size_t)b * DET_ + t) * 4 + 0] = topBox[src * 4 + 0];
    out[((size_t)b * DET_ + t) * 4 + 1] = topBox[src * 4 + 1];
    out[((size_t)b * DET_ + t) * 4 + 2] = topBox[src * 4 + 2];
    out[((size_t)b * DET_ + t) * 4 + 3] = topBox[src * 4 + 3];
    out[B_ * DET_ * 4 + (size_t)b * DET_ + t] = score;
    out[B_ * DET_ * 4 + B_ * DET_ + (size_t)b * DET_ + t] = (float)topLabel[src];
  }
}

extern "C" void kernel_launch(void* const* d_in, const int* in_sizes, int n_in,
                              void* d_out, int out_size, void* d_ws, size_t ws_size,
                              hipStream_t stream) {
  const float* label_pre = (const float*)d_in[0];
  const float* bbox_pre = (const float*)d_in[1];
  const float* props = (const float*)d_in[2];
  float* out = (float*)d_out;

  char* ws = (char*)d_ws;
  size_t off = 0;
  auto alloc = [&](size_t bytes) -> void* {
    void* p = ws + off;
    off = (off + bytes + 255) & ~(size_t)255;
    return p;
  };

  uint32_t* keys = (uint32_t*)alloc((size_t)B_ * NC_ * 4);
  float2* md = (float2*)alloc((size_t)B_ * N_ * 8);
  uint32_t* blockHist = (uint32_t*)alloc((size_t)B_ * IB_ * CB_ * 4);  // fully written
  // ---- zero-init region (one memset): fineHist, cnt, cand ----
  size_t zero_begin = off;
  uint32_t* fineHist = (uint32_t*)alloc((size_t)B_ * FB_ * 4);
  uint32_t* cnt = (uint32_t*)alloc((size_t)B_ * SLOTS_ * 16 * 4);
  u64* cand = (u64*)alloc((size_t)B_ * CAND_ * 8);
  size_t zero_end = off;
  // ------------------------------------------------------------
  uint32_t* thr = (uint32_t*)alloc((size_t)B_ * 4);
  int* coarse = (int*)alloc((size_t)B_ * 4);
  uint32_t* tailA = (uint32_t*)alloc((size_t)B_ * 4);
  float* topScore = (float*)alloc((size_t)B_ * KP_ * 4);
  int* topLabel = (int*)alloc((size_t)B_ * KP_ * 4);
  float* topBox = (float*)alloc((size_t)B_ * KP_ * 16);
  float* nmsBox = (float*)alloc((size_t)B_ * KP_ * 16);
  u64* sup = (u64*)alloc((size_t)B_ * KP_ * NW_ * 8);
  float* finalScore = (float*)alloc((size_t)B_ * KP_ * 4);

  if (off > ws_size) return;  // workspace too small -> fail visibly

  hipMemsetAsync(ws + zero_begin, 0, zero_end - zero_begin, stream);

  k_softmax<<<B_ * N_ / 64, 64, 0, stream>>>(label_pre, md);
  k_scores2<<<B_ * IB_, 256, 0, stream>>>(label_pre, bbox_pre, props, md, keys, blockHist);
  k_select<<<B_, 64, 0, stream>>>(blockHist, coarse, tailA, thr);
  k_refine<<<(B_ * NC_ / 4 + 255) / 256, 256, 0, stream>>>(keys, coarse, fineHist);
  k_select2<<<B_, 64, 0, stream>>>(fineHist, coarse, tailA, thr);
  k_compact<<<(B_ * NC_ / 4 + 255) / 256, 256, 0, stream>>>(keys, thr, cnt, cand);
  k_sort_topk<<<B_, 1024, 0, stream>>>(cand, bbox_pre, props,
                                       topScore, topLabel, topBox, nmsBox);
  k_supmat<<<B_ * 1024, 64, 0, stream>>>(nmsBox, sup);
  k_nms_scan<<<B_, 64, 0, stream>>>(sup, topScore, finalScore);
  k_final<<<B_, 1024, 0, stream>>>(finalScore, topBox, topLabel, out);
}